// Round 1
// baseline (1347.127 us; speedup 1.0000x reference)
//
#include <hip/hip_runtime.h>
#include <math.h>

// Problem constants
#define NB   2
#define SEQ  2048
#define CH   768
#define NH   12
#define HD   64
#define F3   2304
#define LSMAX 4.605170185988092f

// Workspace offsets (floats)
#define QOFF 0
#define KOFF 3145728        // NB*NH*SEQ*HD
#define VOFF 6291456
#define OOFF 9437184        // attn output [N,L,C]

// ---------------------------------------------------------------------------
// GEMM: C[m][f] = sum_k A[m][k]*B[f][k] + bias[f]   (C = A * B^T + b)
// 64x64 tile, 256 threads, 4x4 per thread, K-tile 16. LDS stored [k][row].
// Epilogue 1 (qkv): route f -> (q/k/v, head, d) into ws [N,H,L,D] layout.
// ---------------------------------------------------------------------------
__global__ __launch_bounds__(256) void qkv_gemm(const float* __restrict__ X,
                                                const float* __restrict__ W,
                                                const float* __restrict__ bias,
                                                float* __restrict__ ws)
{
    __shared__ float As[16][68];   // [k][m]
    __shared__ float Bs[16][68];   // [k][f]
    const int t  = threadIdx.x;
    const int tx = t & 15;         // f dim
    const int ty = t >> 4;         // m dim
    const int f0 = blockIdx.x * 64;
    const int m0 = blockIdx.y * 64;
    const int lr = t >> 2;         // 0..63
    const int lc = (t & 3) << 2;   // 0,4,8,12

    float acc[4][4] = {};
    for (int k0 = 0; k0 < CH; k0 += 16) {
        __syncthreads();
        float4 a = *(const float4*)&X[(m0 + lr) * CH + k0 + lc];
        float4 b = *(const float4*)&W[(f0 + lr) * CH + k0 + lc];
        As[lc + 0][lr] = a.x; As[lc + 1][lr] = a.y;
        As[lc + 2][lr] = a.z; As[lc + 3][lr] = a.w;
        Bs[lc + 0][lr] = b.x; Bs[lc + 1][lr] = b.y;
        Bs[lc + 2][lr] = b.z; Bs[lc + 3][lr] = b.w;
        __syncthreads();
#pragma unroll
        for (int kk = 0; kk < 16; ++kk) {
            float4 av = *(const float4*)&As[kk][ty * 4];
            float4 bv = *(const float4*)&Bs[kk][tx * 4];
            float am[4] = {av.x, av.y, av.z, av.w};
            float bm[4] = {bv.x, bv.y, bv.z, bv.w};
#pragma unroll
            for (int i = 0; i < 4; ++i)
#pragma unroll
                for (int j = 0; j < 4; ++j)
                    acc[i][j] += am[i] * bm[j];
        }
    }
    // f0 is 64-aligned so the whole block maps to one (q/k/v, head) pair
    const int t3 = f0 / CH;              // 0=q, 1=k, 2=v
    const int h  = (f0 % CH) >> 6;
    float* dst = ws + (size_t)t3 * 3145728;
    const int d = tx * 4;
#pragma unroll
    for (int i = 0; i < 4; ++i) {
        int m = m0 + ty * 4 + i;
        int n = m >> 11, l = m & 2047;
        float4 v;
        v.x = acc[i][0] + bias[f0 + tx * 4 + 0];
        v.y = acc[i][1] + bias[f0 + tx * 4 + 1];
        v.z = acc[i][2] + bias[f0 + tx * 4 + 2];
        v.w = acc[i][3] + bias[f0 + tx * 4 + 3];
        *(float4*)&dst[(((size_t)n * NH + h) * SEQ + l) * HD + d] = v;
    }
}

// ---------------------------------------------------------------------------
// L2-normalize Q and K rows (D=64, one wave per row), fold exp(min(ls,max))
// into Q. Q rows then K rows are contiguous in ws.
// ---------------------------------------------------------------------------
__global__ __launch_bounds__(256) void norm_qk(float* __restrict__ ws,
                                               const float* __restrict__ logit_scale)
{
    const int wid  = threadIdx.x >> 6;
    const int lane = threadIdx.x & 63;
    const long row = (long)blockIdx.x * 4 + wid;   // 0 .. 2*NB*NH*SEQ-1
    float* p = ws + row * 64;
    float v = p[lane];
    float ss = v * v;
#pragma unroll
    for (int m = 32; m; m >>= 1) ss += __shfl_xor(ss, m, 64);
    float scale = 1.0f / fmaxf(sqrtf(ss), 1e-12f);
    if (row < (long)NB * NH * SEQ) {   // Q row: fold logit scale
        int h = (int)((row / SEQ) % NH);
        scale *= __expf(fminf(logit_scale[h], LSMAX));
    }
    p[lane] = v * scale;
}

// ---------------------------------------------------------------------------
// Flash-style attention: block = (64-query tile, head, batch), 256 threads.
// 64-key chunks; online softmax; PV accumulated in registers.
// ---------------------------------------------------------------------------
__global__ __launch_bounds__(256) void attn(float* __restrict__ ws,
                                            const float* __restrict__ mask,
                                            const float* __restrict__ lscale)
{
    __shared__ float Qs[64][68];    // [q][d]
    __shared__ float KsT[64][68];   // [d][k]
    __shared__ float Vs[64][68];    // [k][d]
    __shared__ float S[64][68];     // [q][k]
    __shared__ float m_s[64], l_s[64], alpha_s[64];

    const int t  = threadIdx.x;
    const int tx = t & 15;          // k (S-GEMM) / d (PV) dim
    const int ty = t >> 4;          // q dim
    const int qb = blockIdx.x * 64;
    const int h  = blockIdx.y, n = blockIdx.z;

    const float* Qg = ws + QOFF + (size_t)((n * NH + h) * SEQ) * HD;
    const float* Kg = ws + KOFF + (size_t)((n * NH + h) * SEQ) * HD;
    const float* Vg = ws + VOFF + (size_t)((n * NH + h) * SEQ) * HD;

    {   // load Q tile [64][64]
        int q = t >> 2, d0 = (t & 3) * 4;
#pragma unroll
        for (int j = 0; j < 4; ++j)
            *(float4*)&Qs[q][d0 + 16 * j] =
                *(const float4*)&Qg[(qb + q) * HD + d0 + 16 * j];
    }
    if (t < 64) { m_s[t] = -1e30f; l_s[t] = 0.f; }
    float O[4][4] = {};

    for (int c0 = 0; c0 < SEQ; c0 += 64) {
        __syncthreads();   // protect LDS reuse from previous iteration
        {   // stage K chunk transposed and V chunk
            int k = t >> 2, d0 = (t & 3) * 4;
#pragma unroll
            for (int j = 0; j < 4; ++j) {
                float4 kv = *(const float4*)&Kg[(c0 + k) * HD + d0 + 16 * j];
                KsT[d0 + 16 * j + 0][k] = kv.x;
                KsT[d0 + 16 * j + 1][k] = kv.y;
                KsT[d0 + 16 * j + 2][k] = kv.z;
                KsT[d0 + 16 * j + 3][k] = kv.w;
                *(float4*)&Vs[k][d0 + 16 * j] =
                    *(const float4*)&Vg[(c0 + k) * HD + d0 + 16 * j];
            }
        }
        __syncthreads();
        // S tile = Q . K^T  (64x64x64)
        float sacc[4][4] = {};
#pragma unroll
        for (int d0 = 0; d0 < 64; d0 += 4) {
            float qa[4][4], ka[4][4];
#pragma unroll
            for (int i = 0; i < 4; ++i) {
                float4 v = *(const float4*)&Qs[ty * 4 + i][d0];
                qa[i][0] = v.x; qa[i][1] = v.y; qa[i][2] = v.z; qa[i][3] = v.w;
            }
#pragma unroll
            for (int dd = 0; dd < 4; ++dd) {
                float4 v = *(const float4*)&KsT[d0 + dd][tx * 4];
                ka[dd][0] = v.x; ka[dd][1] = v.y; ka[dd][2] = v.z; ka[dd][3] = v.w;
            }
#pragma unroll
            for (int i = 0; i < 4; ++i)
#pragma unroll
                for (int j = 0; j < 4; ++j)
#pragma unroll
                    for (int dd = 0; dd < 4; ++dd)
                        sacc[i][j] += qa[i][dd] * ka[dd][j];
        }
#pragma unroll
        for (int i = 0; i < 4; ++i) {
            float4 v = {sacc[i][0], sacc[i][1], sacc[i][2], sacc[i][3]};
            *(float4*)&S[ty * 4 + i][tx * 4] = v;
        }
        __syncthreads();
        // online softmax: wave w owns rows w*16 .. w*16+15
        {
            int w = t >> 6, lane = t & 63;
            for (int j = 0; j < 16; ++j) {
                int r = w * 16 + j;
                float sv = S[r][lane] + mask[(size_t)(qb + r) * SEQ + c0 + lane];
                float mx = sv;
#pragma unroll
                for (int mm = 32; mm; mm >>= 1) mx = fmaxf(mx, __shfl_xor(mx, mm, 64));
                float mold = m_s[r];
                float mnew = fmaxf(mold, mx);
                float p = __expf(sv - mnew);
                float psum = p;
#pragma unroll
                for (int mm = 32; mm; mm >>= 1) psum += __shfl_xor(psum, mm, 64);
                S[r][lane] = p;
                if (lane == 0) {
                    float alpha = __expf(mold - mnew);
                    l_s[r] = l_s[r] * alpha + psum;
                    m_s[r] = mnew;
                    alpha_s[r] = alpha;
                }
            }
        }
        __syncthreads();
        // rescale O, accumulate P.V
        float al[4];
#pragma unroll
        for (int i = 0; i < 4; ++i) al[i] = alpha_s[ty * 4 + i];
#pragma unroll
        for (int i = 0; i < 4; ++i)
#pragma unroll
            for (int j = 0; j < 4; ++j) O[i][j] *= al[i];
        for (int kk = 0; kk < 64; ++kk) {
            float pv[4];
#pragma unroll
            for (int i = 0; i < 4; ++i) pv[i] = S[ty * 4 + i][kk];
            float4 vv = *(const float4*)&Vs[kk][tx * 4];
            float va[4] = {vv.x, vv.y, vv.z, vv.w};
#pragma unroll
            for (int i = 0; i < 4; ++i)
#pragma unroll
                for (int j = 0; j < 4; ++j) O[i][j] += pv[i] * va[j];
        }
    }
    // epilogue: /l, * learned_scale, write [N,L,C] with heads interleaved
    float* Og = ws + OOFF;
    float lsc = lscale[h];
#pragma unroll
    for (int i = 0; i < 4; ++i) {
        int q = qb + ty * 4 + i;
        float inv = lsc / l_s[ty * 4 + i];
        float4 v = {O[i][0] * inv, O[i][1] * inv, O[i][2] * inv, O[i][3] * inv};
        *(float4*)&Og[((size_t)n * SEQ + q) * CH + h * HD + tx * 4] = v;
    }
}

// ---------------------------------------------------------------------------
// Output projection: out = A * W^T + b  (plain epilogue)
// ---------------------------------------------------------------------------
__global__ __launch_bounds__(256) void out_gemm(const float* __restrict__ A,
                                                const float* __restrict__ W,
                                                const float* __restrict__ bias,
                                                float* __restrict__ out)
{
    __shared__ float As[16][68];
    __shared__ float Bs[16][68];
    const int t  = threadIdx.x;
    const int tx = t & 15;
    const int ty = t >> 4;
    const int f0 = blockIdx.x * 64;
    const int m0 = blockIdx.y * 64;
    const int lr = t >> 2;
    const int lc = (t & 3) << 2;

    float acc[4][4] = {};
    for (int k0 = 0; k0 < CH; k0 += 16) {
        __syncthreads();
        float4 a = *(const float4*)&A[(m0 + lr) * CH + k0 + lc];
        float4 b = *(const float4*)&W[(f0 + lr) * CH + k0 + lc];
        As[lc + 0][lr] = a.x; As[lc + 1][lr] = a.y;
        As[lc + 2][lr] = a.z; As[lc + 3][lr] = a.w;
        Bs[lc + 0][lr] = b.x; Bs[lc + 1][lr] = b.y;
        Bs[lc + 2][lr] = b.z; Bs[lc + 3][lr] = b.w;
        __syncthreads();
#pragma unroll
        for (int kk = 0; kk < 16; ++kk) {
            float4 av = *(const float4*)&As[kk][ty * 4];
            float4 bv = *(const float4*)&Bs[kk][tx * 4];
            float am[4] = {av.x, av.y, av.z, av.w};
            float bm[4] = {bv.x, bv.y, bv.z, bv.w};
#pragma unroll
            for (int i = 0; i < 4; ++i)
#pragma unroll
                for (int j = 0; j < 4; ++j)
                    acc[i][j] += am[i] * bm[j];
        }
    }
#pragma unroll
    for (int i = 0; i < 4; ++i) {
        int m = m0 + ty * 4 + i;
        float4 v;
        v.x = acc[i][0] + bias[f0 + tx * 4 + 0];
        v.y = acc[i][1] + bias[f0 + tx * 4 + 1];
        v.z = acc[i][2] + bias[f0 + tx * 4 + 2];
        v.w = acc[i][3] + bias[f0 + tx * 4 + 3];
        *(float4*)&out[(size_t)m * CH + f0 + tx * 4] = v;
    }
}

extern "C" void kernel_launch(void* const* d_in, const int* in_sizes, int n_in,
                              void* d_out, int out_size, void* d_ws, size_t ws_size,
                              hipStream_t stream) {
    const float* x    = (const float*)d_in[0];
    const float* w1   = (const float*)d_in[1];
    const float* b1   = (const float*)d_in[2];
    const float* ls   = (const float*)d_in[3];
    const float* lrn  = (const float*)d_in[4];
    const float* w2   = (const float*)d_in[5];
    const float* b2   = (const float*)d_in[6];
    const float* msk  = (const float*)d_in[7];
    float* ws  = (float*)d_ws;
    float* out = (float*)d_out;

    hipLaunchKernelGGL(qkv_gemm, dim3(F3 / 64, (NB * SEQ) / 64), dim3(256), 0, stream,
                       x, w1, b1, ws);
    hipLaunchKernelGGL(norm_qk, dim3(2 * NB * NH * SEQ / 4), dim3(256), 0, stream,
                       ws, ls);
    hipLaunchKernelGGL(attn, dim3(SEQ / 64, NH, NB), dim3(256), 0, stream,
                       ws, msk, lrn);
    hipLaunchKernelGGL(out_gemm, dim3(CH / 64, (NB * SEQ) / 64), dim3(256), 0, stream,
                       ws + OOFF, w2, b2, out);
}

// Round 2
// 474.949 us; speedup vs baseline: 2.8364x; 2.8364x over previous
//
#include <hip/hip_runtime.h>
#include <math.h>

// Problem constants
#define NB   2
#define SEQ  2048
#define CH   768
#define NH   12
#define HD   64
#define F3   2304
#define LSMAX 4.605170185988092f

typedef _Float16 f16;
typedef __attribute__((ext_vector_type(8))) _Float16 f16x8;
typedef __attribute__((ext_vector_type(4))) _Float16 f16x4;
typedef __attribute__((ext_vector_type(4))) float f32x4;

// fp16 Q/K/V each NB*NH*SEQ*HD elements
#define QSZ 3145728
// attn output [N,L,C] fp32, placed after the 3 fp16 tensors (in float units)
#define OATT 4718592

#define PIT 72   // LDS pitch in f16: rows 144B -> 16B-aligned, b128 reads at bank floor

// ---------------------------------------------------------------------------
// QKV GEMM: C[m][f] = sum_k X[m][k]*W[f][k] + b[f]; epilogue l2-normalizes
// Q/K rows (d=64 lives across 16 adjacent lanes), folds exp(min(ls,MAX)) into
// Q, and writes fp16 [t3][n][h][l][d].
// ---------------------------------------------------------------------------
__global__ __launch_bounds__(256) void qkv_gemm(const float* __restrict__ X,
                                                const float* __restrict__ W,
                                                const float* __restrict__ bias,
                                                const float* __restrict__ logit_scale,
                                                f16* __restrict__ qkv16)
{
    __shared__ float As[16][68];   // [k][m]
    __shared__ float Bs[16][68];   // [k][f]
    const int t  = threadIdx.x;
    const int tx = t & 15;         // f dim
    const int ty = t >> 4;         // m dim
    const int f0 = blockIdx.x * 64;
    const int m0 = blockIdx.y * 64;
    const int lr = t >> 2;
    const int lc = (t & 3) << 2;

    float acc[4][4] = {};
    for (int k0 = 0; k0 < CH; k0 += 16) {
        __syncthreads();
        float4 a = *(const float4*)&X[(m0 + lr) * CH + k0 + lc];
        float4 b = *(const float4*)&W[(f0 + lr) * CH + k0 + lc];
        As[lc + 0][lr] = a.x; As[lc + 1][lr] = a.y;
        As[lc + 2][lr] = a.z; As[lc + 3][lr] = a.w;
        Bs[lc + 0][lr] = b.x; Bs[lc + 1][lr] = b.y;
        Bs[lc + 2][lr] = b.z; Bs[lc + 3][lr] = b.w;
        __syncthreads();
#pragma unroll
        for (int kk = 0; kk < 16; ++kk) {
            float4 av = *(const float4*)&As[kk][ty * 4];
            float4 bv = *(const float4*)&Bs[kk][tx * 4];
            float am[4] = {av.x, av.y, av.z, av.w};
            float bm[4] = {bv.x, bv.y, bv.z, bv.w};
#pragma unroll
            for (int i = 0; i < 4; ++i)
#pragma unroll
                for (int j = 0; j < 4; ++j)
                    acc[i][j] += am[i] * bm[j];
        }
    }
    // f0 64-aligned -> one (q/k/v, head) pair per block
    const int t3 = f0 / CH;              // 0=q, 1=k, 2=v
    const int h  = (f0 % CH) >> 6;
    f16* dst = qkv16 + (size_t)t3 * QSZ;
    float lsv = (t3 == 0) ? __expf(fminf(logit_scale[h], LSMAX)) : 1.0f;
#pragma unroll
    for (int i = 0; i < 4; ++i) {
        int m = m0 + ty * 4 + i;
        int n = m >> 11, l = m & 2047;
        float v0 = acc[i][0] + bias[f0 + tx * 4 + 0];
        float v1 = acc[i][1] + bias[f0 + tx * 4 + 1];
        float v2 = acc[i][2] + bias[f0 + tx * 4 + 2];
        float v3 = acc[i][3] + bias[f0 + tx * 4 + 3];
        float scale = 1.0f;
        if (t3 < 2) {   // l2 norm across the 16 lanes holding this row
            float ss = v0 * v0 + v1 * v1 + v2 * v2 + v3 * v3;
#pragma unroll
            for (int mk = 1; mk < 16; mk <<= 1) ss += __shfl_xor(ss, mk, 64);
            scale = 1.0f / fmaxf(sqrtf(ss), 1e-12f);
            if (t3 == 0) scale *= lsv;
        }
        f16x4 o;
        o[0] = (f16)(v0 * scale); o[1] = (f16)(v1 * scale);
        o[2] = (f16)(v2 * scale); o[3] = (f16)(v3 * scale);
        *(f16x4*)&dst[(((size_t)n * NH + h) * SEQ + l) * HD + tx * 4] = o;
    }
}

// ---------------------------------------------------------------------------
// Flash attention, f16 MFMA 16x16x32. Block = (64 q, head, batch), 4 waves.
// Wave w owns q rows [w*16, w*16+16). Online softmax in registers (C-layout:
// lane holds rows quad*4+r, col sub). P -> LDS fp16 -> A-frag (wave-private).
// ---------------------------------------------------------------------------
__global__ __launch_bounds__(256, 4) void attn(const f16* __restrict__ Qh,
                                               const f16* __restrict__ Kh,
                                               const f16* __restrict__ Vh,
                                               const float* __restrict__ mask,
                                               const float* __restrict__ lscale,
                                               float* __restrict__ Og)
{
    __shared__ f16 Qs[64 * PIT];   // [q][d]
    __shared__ f16 Ks[64 * PIT];   // [key][d]
    __shared__ f16 Vt[64 * PIT];   // [d][key]
    __shared__ f16 Ps[64 * PIT];   // [q][key]

    const int t    = threadIdx.x;
    const int w    = t >> 6;
    const int lane = t & 63;
    const int quad = lane >> 4;
    const int sub  = lane & 15;
    const int qb   = blockIdx.x * 64;
    const int h    = blockIdx.y, n = blockIdx.z;

    const f16* Qg = Qh + ((size_t)(n * NH + h) * SEQ + qb) * HD;
    const f16* Kg = Kh + (size_t)(n * NH + h) * SEQ * HD;
    const f16* Vg = Vh + (size_t)(n * NH + h) * SEQ * HD;

    // stage Q tile
#pragma unroll
    for (int rep = 0; rep < 2; ++rep) {
        int id = rep * 256 + t;
        int row = id >> 3, c8 = id & 7;
        *(f16x8*)&Qs[row * PIT + c8 * 8] = *(const f16x8*)&Qg[row * 64 + c8 * 8];
    }
    __syncthreads();
    // Q fragments persist across all chunks: rows w*16+sub, k = kb*32+quad*8
    f16x8 qf0 = *(const f16x8*)&Qs[(w * 16 + sub) * PIT + quad * 8];
    f16x8 qf1 = *(const f16x8*)&Qs[(w * 16 + sub) * PIT + 32 + quad * 8];

    f32x4 o[4];
    float m_run[4], l_run[4];
#pragma unroll
    for (int dt = 0; dt < 4; ++dt) o[dt] = (f32x4){0.f, 0.f, 0.f, 0.f};
#pragma unroll
    for (int r = 0; r < 4; ++r) { m_run[r] = -1e30f; l_run[r] = 0.f; }

    for (int c0 = 0; c0 < SEQ; c0 += 64) {
        __syncthreads();   // prev chunk's PV reads done before restaging
        // stage K [key][d]
#pragma unroll
        for (int rep = 0; rep < 2; ++rep) {
            int id = rep * 256 + t;
            int row = id >> 3, c8 = id & 7;
            *(f16x8*)&Ks[row * PIT + c8 * 8] =
                *(const f16x8*)&Kg[(c0 + row) * 64 + c8 * 8];
        }
        // stage V transposed [d][key]; wave w covers d0 = w*16 + {0,8};
        // lane-contiguous LDS writes -> conflict-free
#pragma unroll
        for (int rep = 0; rep < 2; ++rep) {
            int d0 = w * 16 + rep * 8;
            f16x8 vv = *(const f16x8*)&Vg[(c0 + lane) * 64 + d0];
#pragma unroll
            for (int j = 0; j < 8; ++j) Vt[(d0 + j) * PIT + lane] = vv[j];
        }
        __syncthreads();

        // S = Q.K^T for this wave's 16 rows x 64 keys
        f32x4 s[4];
#pragma unroll
        for (int ct = 0; ct < 4; ++ct) {
            f16x8 kf0 = *(const f16x8*)&Ks[(ct * 16 + sub) * PIT + quad * 8];
            f16x8 kf1 = *(const f16x8*)&Ks[(ct * 16 + sub) * PIT + 32 + quad * 8];
            f32x4 acc = (f32x4){0.f, 0.f, 0.f, 0.f};
            acc = __builtin_amdgcn_mfma_f32_16x16x32_f16(qf0, kf0, acc, 0, 0, 0);
            acc = __builtin_amdgcn_mfma_f32_16x16x32_f16(qf1, kf1, acc, 0, 0, 0);
            s[ct] = acc;
        }
        // mask add + row stats (rows = qb + w*16 + quad*4 + r, col = ct*16+sub)
        const float* mrow = mask + (size_t)(qb + w * 16 + quad * 4) * SEQ + c0;
        float mnew[4];
#pragma unroll
        for (int r = 0; r < 4; ++r) mnew[r] = m_run[r];
#pragma unroll
        for (int ct = 0; ct < 4; ++ct)
#pragma unroll
            for (int r = 0; r < 4; ++r) {
                s[ct][r] += mrow[(size_t)r * SEQ + ct * 16 + sub];
                mnew[r] = fmaxf(mnew[r], s[ct][r]);
            }
#pragma unroll
        for (int r = 0; r < 4; ++r)
#pragma unroll
            for (int mk = 1; mk < 16; mk <<= 1)
                mnew[r] = fmaxf(mnew[r], __shfl_xor(mnew[r], mk, 64));
        float alpha[4], psum[4];
#pragma unroll
        for (int r = 0; r < 4; ++r) {
            alpha[r] = __expf(m_run[r] - mnew[r]);
            psum[r] = 0.f;
        }
#pragma unroll
        for (int ct = 0; ct < 4; ++ct)
#pragma unroll
            for (int r = 0; r < 4; ++r) {
                float p = __expf(s[ct][r] - mnew[r]);
                s[ct][r] = p;
                psum[r] += p;
            }
#pragma unroll
        for (int r = 0; r < 4; ++r) {
#pragma unroll
            for (int mk = 1; mk < 16; mk <<= 1)
                psum[r] += __shfl_xor(psum[r], mk, 64);
            l_run[r] = l_run[r] * alpha[r] + psum[r];
            m_run[r] = mnew[r];
        }
        // P -> LDS fp16 (wave-private rows; same-wave DS ops are in-order)
#pragma unroll
        for (int ct = 0; ct < 4; ++ct)
#pragma unroll
            for (int r = 0; r < 4; ++r)
                Ps[(w * 16 + quad * 4 + r) * PIT + ct * 16 + sub] = (f16)s[ct][r];
        // rescale O, then O += P.V
#pragma unroll
        for (int dt = 0; dt < 4; ++dt)
#pragma unroll
            for (int r = 0; r < 4; ++r) o[dt][r] *= alpha[r];
        f16x8 pf0 = *(const f16x8*)&Ps[(w * 16 + sub) * PIT + quad * 8];
        f16x8 pf1 = *(const f16x8*)&Ps[(w * 16 + sub) * PIT + 32 + quad * 8];
#pragma unroll
        for (int dt = 0; dt < 4; ++dt) {
            f16x8 vf0 = *(const f16x8*)&Vt[(dt * 16 + sub) * PIT + quad * 8];
            f16x8 vf1 = *(const f16x8*)&Vt[(dt * 16 + sub) * PIT + 32 + quad * 8];
            o[dt] = __builtin_amdgcn_mfma_f32_16x16x32_f16(pf0, vf0, o[dt], 0, 0, 0);
            o[dt] = __builtin_amdgcn_mfma_f32_16x16x32_f16(pf1, vf1, o[dt], 0, 0, 0);
        }
    }
    // epilogue: * learned_scale / l, write [N,L,C] fp32
    float lsc = lscale[h];
#pragma unroll
    for (int r = 0; r < 4; ++r) {
        float inv = lsc / l_run[r];
        int q = qb + w * 16 + quad * 4 + r;
#pragma unroll
        for (int dt = 0; dt < 4; ++dt)
            Og[((size_t)n * SEQ + q) * CH + h * 64 + dt * 16 + sub] = o[dt][r] * inv;
    }
}

// ---------------------------------------------------------------------------
// Output projection: out = A * W^T + b (fp32)
// ---------------------------------------------------------------------------
__global__ __launch_bounds__(256) void out_gemm(const float* __restrict__ A,
                                                const float* __restrict__ W,
                                                const float* __restrict__ bias,
                                                float* __restrict__ out)
{
    __shared__ float As[16][68];
    __shared__ float Bs[16][68];
    const int t  = threadIdx.x;
    const int tx = t & 15;
    const int ty = t >> 4;
    const int f0 = blockIdx.x * 64;
    const int m0 = blockIdx.y * 64;
    const int lr = t >> 2;
    const int lc = (t & 3) << 2;

    float acc[4][4] = {};
    for (int k0 = 0; k0 < CH; k0 += 16) {
        __syncthreads();
        float4 a = *(const float4*)&A[(m0 + lr) * CH + k0 + lc];
        float4 b = *(const float4*)&W[(f0 + lr) * CH + k0 + lc];
        As[lc + 0][lr] = a.x; As[lc + 1][lr] = a.y;
        As[lc + 2][lr] = a.z; As[lc + 3][lr] = a.w;
        Bs[lc + 0][lr] = b.x; Bs[lc + 1][lr] = b.y;
        Bs[lc + 2][lr] = b.z; Bs[lc + 3][lr] = b.w;
        __syncthreads();
#pragma unroll
        for (int kk = 0; kk < 16; ++kk) {
            float4 av = *(const float4*)&As[kk][ty * 4];
            float4 bv = *(const float4*)&Bs[kk][tx * 4];
            float am[4] = {av.x, av.y, av.z, av.w};
            float bm[4] = {bv.x, bv.y, bv.z, bv.w};
#pragma unroll
            for (int i = 0; i < 4; ++i)
#pragma unroll
                for (int j = 0; j < 4; ++j)
                    acc[i][j] += am[i] * bm[j];
        }
    }
#pragma unroll
    for (int i = 0; i < 4; ++i) {
        int m = m0 + ty * 4 + i;
        float4 v;
        v.x = acc[i][0] + bias[f0 + tx * 4 + 0];
        v.y = acc[i][1] + bias[f0 + tx * 4 + 1];
        v.z = acc[i][2] + bias[f0 + tx * 4 + 2];
        v.w = acc[i][3] + bias[f0 + tx * 4 + 3];
        *(float4*)&out[(size_t)m * CH + f0 + tx * 4] = v;
    }
}

extern "C" void kernel_launch(void* const* d_in, const int* in_sizes, int n_in,
                              void* d_out, int out_size, void* d_ws, size_t ws_size,
                              hipStream_t stream) {
    const float* x    = (const float*)d_in[0];
    const float* w1   = (const float*)d_in[1];
    const float* b1   = (const float*)d_in[2];
    const float* ls   = (const float*)d_in[3];
    const float* lrn  = (const float*)d_in[4];
    const float* w2   = (const float*)d_in[5];
    const float* b2   = (const float*)d_in[6];
    const float* msk  = (const float*)d_in[7];
    float* wsf   = (float*)d_ws;
    f16*   qkv16 = (f16*)d_ws;
    float* out   = (float*)d_out;

    hipLaunchKernelGGL(qkv_gemm, dim3(F3 / 64, (NB * SEQ) / 64), dim3(256), 0, stream,
                       x, w1, b1, ls, qkv16);
    hipLaunchKernelGGL(attn, dim3(SEQ / 64, NH, NB), dim3(256), 0, stream,
                       qkv16, qkv16 + QSZ, qkv16 + 2 * QSZ, msk, lrn, wsf + OATT);
    hipLaunchKernelGGL(out_gemm, dim3(CH / 64, (NB * SEQ) / 64), dim3(256), 0, stream,
                       wsf + OATT, w2, b2, out);
}

// Round 3
// 300.939 us; speedup vs baseline: 4.4764x; 1.5782x over previous
//
#include <hip/hip_runtime.h>
#include <math.h>

// Problem constants
#define NB   2
#define SEQ  2048
#define CH   768
#define NH   12
#define HD   64
#define F3   2304
#define LSMAX 4.605170185988092f

typedef _Float16 f16;
typedef __attribute__((ext_vector_type(8))) _Float16 f16x8;
typedef __attribute__((ext_vector_type(4))) _Float16 f16x4;
typedef __attribute__((ext_vector_type(4))) float f32x4;

// f16 workspace layout (units: f16 elements)
#define QSZ  3145728            // NB*NH*SEQ*HD per tensor
#define OATT (3 * QSZ)          // attn output [N,L,C] f16
// LDS pitches
#define PIT  72   // attn Q/K/V tiles: 144B rows, 16B-aligned
#define PPIT 76   // attn P tile: conflict-free scalar writes, b64 reads
#define GP   40   // GEMM LDS pitch (f16): 80B rows, 16B-aligned b128 frags

// ---------------------------------------------------------------------------
// f16-MFMA GEMM template body: C[128x128] per block = A(MxK) * W(NxK)^T.
// 4 waves in 2x2; each wave 64x64 via 4x4 grid of 16x16x32 MFMAs, BK=32.
// A and W are fp32 in global; converted to f16 while staging into LDS.
// ---------------------------------------------------------------------------
__global__ __launch_bounds__(256, 2) void qkv_gemm(const float* __restrict__ X,
                                                   const float* __restrict__ W,
                                                   const float* __restrict__ bias,
                                                   const float* __restrict__ logit_scale,
                                                   f16* __restrict__ qkv16)
{
    __shared__ f16 As[128 * GP];
    __shared__ f16 Bs[128 * GP];
    const int t    = threadIdx.x;
    const int w    = t >> 6;
    const int lane = t & 63;
    const int quad = lane >> 4;
    const int sub  = lane & 15;
    const int wm   = w & 1, wn = w >> 1;
    const int f0   = blockIdx.x * 128;
    const int m0   = blockIdx.y * 128;
    const int srow = t >> 1;            // staging row 0..127
    const int skq  = (t & 1) * 16;      // staging k offset 0/16

    f32x4 acc[4][4];
#pragma unroll
    for (int i = 0; i < 4; ++i)
#pragma unroll
        for (int j = 0; j < 4; ++j) acc[i][j] = (f32x4){0.f, 0.f, 0.f, 0.f};

    for (int k0 = 0; k0 < CH; k0 += 32) {
        float4 a4[4], b4[4];
#pragma unroll
        for (int j = 0; j < 4; ++j) {
            a4[j] = *(const float4*)&X[(size_t)(m0 + srow) * CH + k0 + skq + 4 * j];
            b4[j] = *(const float4*)&W[(size_t)(f0 + srow) * CH + k0 + skq + 4 * j];
        }
        __syncthreads();
#pragma unroll
        for (int j = 0; j < 4; ++j) {
            f16x4 av = {(f16)a4[j].x, (f16)a4[j].y, (f16)a4[j].z, (f16)a4[j].w};
            f16x4 bv = {(f16)b4[j].x, (f16)b4[j].y, (f16)b4[j].z, (f16)b4[j].w};
            *(f16x4*)&As[srow * GP + skq + 4 * j] = av;
            *(f16x4*)&Bs[srow * GP + skq + 4 * j] = bv;
        }
        __syncthreads();
        f16x8 af[4], bf[4];
#pragma unroll
        for (int i = 0; i < 4; ++i) {
            af[i] = *(const f16x8*)&As[(wm * 64 + i * 16 + sub) * GP + quad * 8];
            bf[i] = *(const f16x8*)&Bs[(wn * 64 + i * 16 + sub) * GP + quad * 8];
        }
#pragma unroll
        for (int i = 0; i < 4; ++i)
#pragma unroll
            for (int j = 0; j < 4; ++j)
                acc[i][j] = __builtin_amdgcn_mfma_f32_16x16x32_f16(af[i], bf[j], acc[i][j], 0, 0, 0);
    }

    // epilogue: bias, l2-norm Q/K rows (d=64 = 4 n-tiles x 16 subs), fold ls
    const int t3 = f0 / CH;                       // 0=q,1=k,2=v (block-uniform)
    const int h  = ((f0 + wn * 64) % CH) >> 6;    // wave-uniform head
    f16* dst = qkv16 + (size_t)t3 * QSZ;
    float lsv = (t3 == 0) ? __expf(fminf(logit_scale[h], LSMAX)) : 1.0f;
    float bb[4];
#pragma unroll
    for (int j = 0; j < 4; ++j) bb[j] = bias[f0 + wn * 64 + j * 16 + sub];
#pragma unroll
    for (int i = 0; i < 4; ++i) {
#pragma unroll
        for (int r = 0; r < 4; ++r) {
            int m = m0 + wm * 64 + i * 16 + quad * 4 + r;
            int n = m >> 11, l = m & 2047;
            float v[4];
#pragma unroll
            for (int j = 0; j < 4; ++j) v[j] = acc[i][j][r] + bb[j];
            float scale = 1.0f;
            if (t3 < 2) {
                float ss = v[0] * v[0] + v[1] * v[1] + v[2] * v[2] + v[3] * v[3];
#pragma unroll
                for (int mk = 1; mk < 16; mk <<= 1) ss += __shfl_xor(ss, mk, 64);
                scale = 1.0f / fmaxf(sqrtf(ss), 1e-12f);
                if (t3 == 0) scale *= lsv;
            }
            f16* drow = dst + (((size_t)n * NH + h) * SEQ + l) * HD;
#pragma unroll
            for (int j = 0; j < 4; ++j)
                drow[j * 16 + sub] = (f16)(v[j] * scale);
        }
    }
}

// ---------------------------------------------------------------------------
// Flash attention, f16 MFMA. Ps uses pitch 76: conflict-free scalar writes,
// b64 fragment reads. Output written f16 [N,L,C].
// ---------------------------------------------------------------------------
__global__ __launch_bounds__(256, 4) void attn(const f16* __restrict__ Qh,
                                               const f16* __restrict__ Kh,
                                               const f16* __restrict__ Vh,
                                               const float* __restrict__ mask,
                                               const float* __restrict__ lscale,
                                               f16* __restrict__ Og)
{
    __shared__ f16 Qs[64 * PIT];
    __shared__ f16 Ks[64 * PIT];
    __shared__ f16 Vt[64 * PIT];
    __shared__ f16 Ps[64 * PPIT];

    const int t    = threadIdx.x;
    const int w    = t >> 6;
    const int lane = t & 63;
    const int quad = lane >> 4;
    const int sub  = lane & 15;
    const int qb   = blockIdx.x * 64;
    const int h    = blockIdx.y, n = blockIdx.z;

    const f16* Qg = Qh + ((size_t)(n * NH + h) * SEQ + qb) * HD;
    const f16* Kg = Kh + (size_t)(n * NH + h) * SEQ * HD;
    const f16* Vg = Vh + (size_t)(n * NH + h) * SEQ * HD;

#pragma unroll
    for (int rep = 0; rep < 2; ++rep) {
        int id = rep * 256 + t;
        int row = id >> 3, c8 = id & 7;
        *(f16x8*)&Qs[row * PIT + c8 * 8] = *(const f16x8*)&Qg[row * 64 + c8 * 8];
    }
    __syncthreads();
    f16x8 qf0 = *(const f16x8*)&Qs[(w * 16 + sub) * PIT + quad * 8];
    f16x8 qf1 = *(const f16x8*)&Qs[(w * 16 + sub) * PIT + 32 + quad * 8];

    f32x4 o[4];
    float m_run[4], l_run[4];
#pragma unroll
    for (int dt = 0; dt < 4; ++dt) o[dt] = (f32x4){0.f, 0.f, 0.f, 0.f};
#pragma unroll
    for (int r = 0; r < 4; ++r) { m_run[r] = -1e30f; l_run[r] = 0.f; }

    for (int c0 = 0; c0 < SEQ; c0 += 64) {
        __syncthreads();
#pragma unroll
        for (int rep = 0; rep < 2; ++rep) {
            int id = rep * 256 + t;
            int row = id >> 3, c8 = id & 7;
            *(f16x8*)&Ks[row * PIT + c8 * 8] =
                *(const f16x8*)&Kg[(c0 + row) * 64 + c8 * 8];
        }
#pragma unroll
        for (int rep = 0; rep < 2; ++rep) {
            int d0 = w * 16 + rep * 8;
            f16x8 vv = *(const f16x8*)&Vg[(c0 + lane) * 64 + d0];
#pragma unroll
            for (int j = 0; j < 8; ++j) Vt[(d0 + j) * PIT + lane] = vv[j];
        }
        __syncthreads();

        f32x4 s[4];
#pragma unroll
        for (int ct = 0; ct < 4; ++ct) {
            f16x8 kf0 = *(const f16x8*)&Ks[(ct * 16 + sub) * PIT + quad * 8];
            f16x8 kf1 = *(const f16x8*)&Ks[(ct * 16 + sub) * PIT + 32 + quad * 8];
            f32x4 a = (f32x4){0.f, 0.f, 0.f, 0.f};
            a = __builtin_amdgcn_mfma_f32_16x16x32_f16(qf0, kf0, a, 0, 0, 0);
            a = __builtin_amdgcn_mfma_f32_16x16x32_f16(qf1, kf1, a, 0, 0, 0);
            s[ct] = a;
        }
        const float* mrow = mask + (size_t)(qb + w * 16 + quad * 4) * SEQ + c0;
        float mnew[4];
#pragma unroll
        for (int r = 0; r < 4; ++r) mnew[r] = m_run[r];
#pragma unroll
        for (int ct = 0; ct < 4; ++ct)
#pragma unroll
            for (int r = 0; r < 4; ++r) {
                s[ct][r] += mrow[(size_t)r * SEQ + ct * 16 + sub];
                mnew[r] = fmaxf(mnew[r], s[ct][r]);
            }
#pragma unroll
        for (int r = 0; r < 4; ++r)
#pragma unroll
            for (int mk = 1; mk < 16; mk <<= 1)
                mnew[r] = fmaxf(mnew[r], __shfl_xor(mnew[r], mk, 64));
        float alpha[4], psum[4];
#pragma unroll
        for (int r = 0; r < 4; ++r) {
            alpha[r] = __expf(m_run[r] - mnew[r]);
            psum[r] = 0.f;
        }
#pragma unroll
        for (int ct = 0; ct < 4; ++ct)
#pragma unroll
            for (int r = 0; r < 4; ++r) {
                float p = __expf(s[ct][r] - mnew[r]);
                s[ct][r] = p;
                psum[r] += p;
            }
#pragma unroll
        for (int r = 0; r < 4; ++r) {
#pragma unroll
            for (int mk = 1; mk < 16; mk <<= 1)
                psum[r] += __shfl_xor(psum[r], mk, 64);
            l_run[r] = l_run[r] * alpha[r] + psum[r];
            m_run[r] = mnew[r];
        }
#pragma unroll
        for (int ct = 0; ct < 4; ++ct)
#pragma unroll
            for (int r = 0; r < 4; ++r)
                Ps[(w * 16 + quad * 4 + r) * PPIT + ct * 16 + sub] = (f16)s[ct][r];
#pragma unroll
        for (int dt = 0; dt < 4; ++dt)
#pragma unroll
            for (int r = 0; r < 4; ++r) o[dt][r] *= alpha[r];
        // P fragments: two b64 halves each (rows are wave-private)
        f16x4 p00 = *(const f16x4*)&Ps[(w * 16 + sub) * PPIT + quad * 8];
        f16x4 p01 = *(const f16x4*)&Ps[(w * 16 + sub) * PPIT + quad * 8 + 4];
        f16x4 p10 = *(const f16x4*)&Ps[(w * 16 + sub) * PPIT + 32 + quad * 8];
        f16x4 p11 = *(const f16x4*)&Ps[(w * 16 + sub) * PPIT + 32 + quad * 8 + 4];
        f16x8 pf0 = {p00[0], p00[1], p00[2], p00[3], p01[0], p01[1], p01[2], p01[3]};
        f16x8 pf1 = {p10[0], p10[1], p10[2], p10[3], p11[0], p11[1], p11[2], p11[3]};
#pragma unroll
        for (int dt = 0; dt < 4; ++dt) {
            f16x8 vf0 = *(const f16x8*)&Vt[(dt * 16 + sub) * PIT + quad * 8];
            f16x8 vf1 = *(const f16x8*)&Vt[(dt * 16 + sub) * PIT + 32 + quad * 8];
            o[dt] = __builtin_amdgcn_mfma_f32_16x16x32_f16(pf0, vf0, o[dt], 0, 0, 0);
            o[dt] = __builtin_amdgcn_mfma_f32_16x16x32_f16(pf1, vf1, o[dt], 0, 0, 0);
        }
    }
    float lsc = lscale[h];
#pragma unroll
    for (int r = 0; r < 4; ++r) {
        float inv = lsc / l_run[r];
        int q = qb + w * 16 + quad * 4 + r;
#pragma unroll
        for (int dt = 0; dt < 4; ++dt)
            Og[((size_t)n * SEQ + q) * CH + h * 64 + dt * 16 + sub] =
                (f16)(o[dt][r] * inv);
    }
}

// ---------------------------------------------------------------------------
// Output projection: out = A(f16) * W2(fp32->f16)^T + b, fp32 out.
// ---------------------------------------------------------------------------
__global__ __launch_bounds__(256, 2) void out_gemm(const f16* __restrict__ A,
                                                   const float* __restrict__ W,
                                                   const float* __restrict__ bias,
                                                   float* __restrict__ out)
{
    __shared__ f16 As[128 * GP];
    __shared__ f16 Bs[128 * GP];
    const int t    = threadIdx.x;
    const int w    = t >> 6;
    const int lane = t & 63;
    const int quad = lane >> 4;
    const int sub  = lane & 15;
    const int wm   = w & 1, wn = w >> 1;
    const int f0   = blockIdx.x * 128;
    const int m0   = blockIdx.y * 128;
    const int srow = t >> 1;
    const int skq  = (t & 1) * 16;

    f32x4 acc[4][4];
#pragma unroll
    for (int i = 0; i < 4; ++i)
#pragma unroll
        for (int j = 0; j < 4; ++j) acc[i][j] = (f32x4){0.f, 0.f, 0.f, 0.f};

    for (int k0 = 0; k0 < CH; k0 += 32) {
        f16x8 a8[2];
        float4 b4[4];
        a8[0] = *(const f16x8*)&A[(size_t)(m0 + srow) * CH + k0 + skq];
        a8[1] = *(const f16x8*)&A[(size_t)(m0 + srow) * CH + k0 + skq + 8];
#pragma unroll
        for (int j = 0; j < 4; ++j)
            b4[j] = *(const float4*)&W[(size_t)(f0 + srow) * CH + k0 + skq + 4 * j];
        __syncthreads();
        *(f16x8*)&As[srow * GP + skq + 0] = a8[0];
        *(f16x8*)&As[srow * GP + skq + 8] = a8[1];
#pragma unroll
        for (int j = 0; j < 4; ++j) {
            f16x4 bv = {(f16)b4[j].x, (f16)b4[j].y, (f16)b4[j].z, (f16)b4[j].w};
            *(f16x4*)&Bs[srow * GP + skq + 4 * j] = bv;
        }
        __syncthreads();
        f16x8 af[4], bf[4];
#pragma unroll
        for (int i = 0; i < 4; ++i) {
            af[i] = *(const f16x8*)&As[(wm * 64 + i * 16 + sub) * GP + quad * 8];
            bf[i] = *(const f16x8*)&Bs[(wn * 64 + i * 16 + sub) * GP + quad * 8];
        }
#pragma unroll
        for (int i = 0; i < 4; ++i)
#pragma unroll
            for (int j = 0; j < 4; ++j)
                acc[i][j] = __builtin_amdgcn_mfma_f32_16x16x32_f16(af[i], bf[j], acc[i][j], 0, 0, 0);
    }
    float bb[4];
#pragma unroll
    for (int j = 0; j < 4; ++j) bb[j] = bias[f0 + wn * 64 + j * 16 + sub];
#pragma unroll
    for (int i = 0; i < 4; ++i)
#pragma unroll
        for (int r = 0; r < 4; ++r) {
            int m = m0 + wm * 64 + i * 16 + quad * 4 + r;
            float* orow = out + (size_t)m * CH + f0 + wn * 64;
#pragma unroll
            for (int j = 0; j < 4; ++j)
                orow[j * 16 + sub] = acc[i][j][r] + bb[j];
        }
}

extern "C" void kernel_launch(void* const* d_in, const int* in_sizes, int n_in,
                              void* d_out, int out_size, void* d_ws, size_t ws_size,
                              hipStream_t stream) {
    const float* x    = (const float*)d_in[0];
    const float* w1   = (const float*)d_in[1];
    const float* b1   = (const float*)d_in[2];
    const float* ls   = (const float*)d_in[3];
    const float* lrn  = (const float*)d_in[4];
    const float* w2   = (const float*)d_in[5];
    const float* b2   = (const float*)d_in[6];
    const float* msk  = (const float*)d_in[7];
    f16*   qkv16 = (f16*)d_ws;
    float* out   = (float*)d_out;

    hipLaunchKernelGGL(qkv_gemm, dim3(F3 / 128, (NB * SEQ) / 128), dim3(256), 0, stream,
                       x, w1, b1, ls, qkv16);
    hipLaunchKernelGGL(attn, dim3(SEQ / 64, NH, NB), dim3(256), 0, stream,
                       qkv16, qkv16 + QSZ, qkv16 + 2 * QSZ, msk, lrn, qkv16 + OATT);
    hipLaunchKernelGGL(out_gemm, dim3(CH / 128, (NB * SEQ) / 128), dim3(256), 0, stream,
                       qkv16 + OATT, w2, b2, out);
}

// Round 4
// 230.102 us; speedup vs baseline: 5.8545x; 1.3079x over previous
//
#include <hip/hip_runtime.h>
#include <math.h>

// Problem constants
#define NB   2
#define SEQ  2048
#define CH   768
#define NH   12
#define HD   64
#define F3   2304
#define LSMAX 4.605170185988092f

typedef _Float16 f16;
typedef __attribute__((ext_vector_type(8))) _Float16 f16x8;
typedef __attribute__((ext_vector_type(4))) _Float16 f16x4;
typedef __attribute__((ext_vector_type(4))) float f32x4;

// f16 workspace layout (units: f16 elements)
#define QSZ   3145728                 // per Q/K/V tensor
#define OATT  (3 * QSZ)               // attn out [N,L,C] f16 (3145728)
#define XHOFF 12582912                // x -> f16 (3145728)
#define W1OFF 15728640                // in_proj_w -> f16 (1769472)
#define W2OFF 17498112                // out_proj_w -> f16 (589824)
#define MOFF  18087936                // mask -> f16 (4194304)

// LDS pitches
#define PIT  72   // attn K/V tiles: 144B rows, 16B-aligned (b128 ok)
#define PPIT 76   // attn Q/P tile: 152B rows, 8B-aligned (b64 ops only)
#define GP   40   // GEMM tiles: 80B rows, 16B-aligned (b128 ok, bank-floor)

// ---------------------------------------------------------------------------
// One-shot fp32 -> f16 convert of X, W1, W2, mask.
// ---------------------------------------------------------------------------
__global__ __launch_bounds__(256) void cvt_f16(const float* __restrict__ X,
                                               const float* __restrict__ W1,
                                               const float* __restrict__ W2,
                                               const float* __restrict__ M,
                                               f16* __restrict__ Xh,
                                               f16* __restrict__ W1h,
                                               f16* __restrict__ W2h,
                                               f16* __restrict__ Mh)
{
    int tid = blockIdx.x * 256 + threadIdx.x;
    const float* src; f16* dst; int n4;
    switch (blockIdx.y) {
        case 0:  src = X;  dst = Xh;  n4 = 786432;  break;
        case 1:  src = W1; dst = W1h; n4 = 442368;  break;
        case 2:  src = W2; dst = W2h; n4 = 147456;  break;
        default: src = M;  dst = Mh;  n4 = 1048576; break;
    }
    if (tid < n4) {
        float4 v = ((const float4*)src)[tid];
        f16x4 o = {(f16)v.x, (f16)v.y, (f16)v.z, (f16)v.w};
        ((f16x4*)dst)[tid] = o;
    }
}

// ---------------------------------------------------------------------------
// QKV GEMM, f16 inputs, reg-prefetched staging. 128x128 tile, 4 waves 2x2,
// BK=32, 16x16x32 MFMA. Epilogue: bias, l2-norm Q/K rows, fold logit scale.
// ---------------------------------------------------------------------------
__global__ __launch_bounds__(256, 3) void qkv_gemm(const f16* __restrict__ Xh,
                                                   const f16* __restrict__ Wh,
                                                   const float* __restrict__ bias,
                                                   const float* __restrict__ logit_scale,
                                                   f16* __restrict__ qkv16)
{
    __shared__ f16 As[128 * GP];
    __shared__ f16 Bs[128 * GP];
    const int t    = threadIdx.x;
    const int w    = t >> 6;
    const int lane = t & 63;
    const int quad = lane >> 4;
    const int sub  = lane & 15;
    const int wm   = w & 1, wn = w >> 1;
    const int f0   = blockIdx.x * 128;
    const int m0   = blockIdx.y * 128;
    const int srow = t >> 1;
    const int sk   = (t & 1) * 16;

    const f16* ag = Xh + (size_t)(m0 + srow) * CH + sk;
    const f16* bg = Wh + (size_t)(f0 + srow) * CH + sk;
    f16x8 a0 = *(const f16x8*)(ag);
    f16x8 a1 = *(const f16x8*)(ag + 8);
    f16x8 b0 = *(const f16x8*)(bg);
    f16x8 b1 = *(const f16x8*)(bg + 8);

    f32x4 acc[4][4];
#pragma unroll
    for (int i = 0; i < 4; ++i)
#pragma unroll
        for (int j = 0; j < 4; ++j) acc[i][j] = (f32x4){0.f, 0.f, 0.f, 0.f};

    for (int k0 = 0; k0 < CH; k0 += 32) {
        __syncthreads();
        *(f16x8*)&As[srow * GP + sk + 0] = a0;
        *(f16x8*)&As[srow * GP + sk + 8] = a1;
        *(f16x8*)&Bs[srow * GP + sk + 0] = b0;
        *(f16x8*)&Bs[srow * GP + sk + 8] = b1;
        __syncthreads();
        if (k0 + 32 < CH) {
            a0 = *(const f16x8*)(ag + k0 + 32);
            a1 = *(const f16x8*)(ag + k0 + 40);
            b0 = *(const f16x8*)(bg + k0 + 32);
            b1 = *(const f16x8*)(bg + k0 + 40);
        }
        f16x8 af[4], bf[4];
#pragma unroll
        for (int i = 0; i < 4; ++i) {
            af[i] = *(const f16x8*)&As[(wm * 64 + i * 16 + sub) * GP + quad * 8];
            bf[i] = *(const f16x8*)&Bs[(wn * 64 + i * 16 + sub) * GP + quad * 8];
        }
#pragma unroll
        for (int i = 0; i < 4; ++i)
#pragma unroll
            for (int j = 0; j < 4; ++j)
                acc[i][j] = __builtin_amdgcn_mfma_f32_16x16x32_f16(af[i], bf[j], acc[i][j], 0, 0, 0);
    }

    const int t3 = f0 / CH;                       // 0=q,1=k,2=v (block-uniform)
    const int h  = ((f0 + wn * 64) % CH) >> 6;    // wave-uniform head
    f16* dst = qkv16 + (size_t)t3 * QSZ;
    float lsv = (t3 == 0) ? __expf(fminf(logit_scale[h], LSMAX)) : 1.0f;
    float bb[4];
#pragma unroll
    for (int j = 0; j < 4; ++j) bb[j] = bias[f0 + wn * 64 + j * 16 + sub];
#pragma unroll
    for (int i = 0; i < 4; ++i) {
#pragma unroll
        for (int r = 0; r < 4; ++r) {
            int m = m0 + wm * 64 + i * 16 + quad * 4 + r;
            int n = m >> 11, l = m & 2047;
            float v[4];
#pragma unroll
            for (int j = 0; j < 4; ++j) v[j] = acc[i][j][r] + bb[j];
            float scale = 1.0f;
            if (t3 < 2) {
                float ss = v[0] * v[0] + v[1] * v[1] + v[2] * v[2] + v[3] * v[3];
#pragma unroll
                for (int mk = 1; mk < 16; mk <<= 1) ss += __shfl_xor(ss, mk, 64);
                scale = 1.0f / fmaxf(sqrtf(ss), 1e-12f);
                if (t3 == 0) scale *= lsv;
            }
            f16* drow = dst + (((size_t)n * NH + h) * SEQ + l) * HD;
#pragma unroll
            for (int j = 0; j < 4; ++j)
                drow[j * 16 + sub] = (f16)(v[j] * scale);
        }
    }
}

// ---------------------------------------------------------------------------
// Flash attention, f16 MFMA, software-pipelined: K/V/mask for chunk c+1 are
// prefetched into registers during chunk c's compute. Per-lane partial l
// (alpha is row-uniform), single reduce at the end. Q/P share one LDS tile.
// ---------------------------------------------------------------------------
__global__ __launch_bounds__(256, 3) void attn(const f16* __restrict__ Qh,
                                               const f16* __restrict__ Kh,
                                               const f16* __restrict__ Vh,
                                               const f16* __restrict__ Mh,
                                               const float* __restrict__ lscale,
                                               f16* __restrict__ Og)
{
    __shared__ f16 Ks[64 * PIT];
    __shared__ f16 Vt[64 * PIT];
    __shared__ f16 QP[64 * PPIT];   // Q tile, then reused as P tile

    const int t    = threadIdx.x;
    const int w    = t >> 6;
    const int lane = t & 63;
    const int quad = lane >> 4;
    const int sub  = lane & 15;
    const int qb   = blockIdx.x * 64;
    const int h    = blockIdx.y, n = blockIdx.z;

    const f16* Qg = Qh + ((size_t)(n * NH + h) * SEQ + qb) * HD;
    const f16* Kg = Kh + (size_t)(n * NH + h) * SEQ * HD;
    const f16* Vg = Vh + (size_t)(n * NH + h) * SEQ * HD;
    const f16* Mg = Mh + (size_t)(qb + w * 16 + quad * 4) * SEQ;

    // stage Q (b128 global loads, b64 LDS stores: PPIT rows are 8B-aligned)
#pragma unroll
    for (int rep = 0; rep < 2; ++rep) {
        int id = rep * 256 + t;
        int row = id >> 3, c8 = id & 7;
        f16x8 v = *(const f16x8*)&Qg[row * 64 + c8 * 8];
        *(f16x4*)&QP[row * PPIT + c8 * 8 + 0] = (f16x4){v[0], v[1], v[2], v[3]};
        *(f16x4*)&QP[row * PPIT + c8 * 8 + 4] = (f16x4){v[4], v[5], v[6], v[7]};
    }
    __syncthreads();
    f16x8 qf0, qf1;
    {
        f16x4 l0 = *(const f16x4*)&QP[(w * 16 + sub) * PPIT + quad * 8];
        f16x4 l1 = *(const f16x4*)&QP[(w * 16 + sub) * PPIT + quad * 8 + 4];
        f16x4 l2 = *(const f16x4*)&QP[(w * 16 + sub) * PPIT + 32 + quad * 8];
        f16x4 l3 = *(const f16x4*)&QP[(w * 16 + sub) * PPIT + 32 + quad * 8 + 4];
        qf0 = (f16x8){l0[0], l0[1], l0[2], l0[3], l1[0], l1[1], l1[2], l1[3]};
        qf1 = (f16x8){l2[0], l2[1], l2[2], l2[3], l3[0], l3[1], l3[2], l3[3]};
    }

    // prefetch chunk 0: K (2 b128), V (2 b128), mask (16 f16)
    const int krow = t >> 3, kc8 = t & 7;
    f16x8 kr0 = *(const f16x8*)&Kg[krow * 64 + kc8 * 8];
    f16x8 kr1 = *(const f16x8*)&Kg[(32 + krow) * 64 + kc8 * 8];
    f16x8 vr0 = *(const f16x8*)&Vg[lane * 64 + w * 16];
    f16x8 vr1 = *(const f16x8*)&Vg[lane * 64 + w * 16 + 8];
    f16 mnxt[16];
#pragma unroll
    for (int ct = 0; ct < 4; ++ct)
#pragma unroll
        for (int r = 0; r < 4; ++r)
            mnxt[ct * 4 + r] = Mg[(size_t)r * SEQ + ct * 16 + sub];

    f32x4 o[4];
    float m_run[4], l_lane[4];
#pragma unroll
    for (int dt = 0; dt < 4; ++dt) o[dt] = (f32x4){0.f, 0.f, 0.f, 0.f};
#pragma unroll
    for (int r = 0; r < 4; ++r) { m_run[r] = -1e30f; l_lane[r] = 0.f; }

    for (int c0 = 0; c0 < SEQ; c0 += 64) {
        __syncthreads();   // prev chunk's LDS reads done
        *(f16x8*)&Ks[krow * PIT + kc8 * 8] = kr0;
        *(f16x8*)&Ks[(32 + krow) * PIT + kc8 * 8] = kr1;
#pragma unroll
        for (int j = 0; j < 8; ++j) {
            Vt[(w * 16 + j) * PIT + lane] = vr0[j];
            Vt[(w * 16 + 8 + j) * PIT + lane] = vr1[j];
        }
        __syncthreads();

        f16 mcur[16];
#pragma unroll
        for (int i = 0; i < 16; ++i) mcur[i] = mnxt[i];
        if (c0 + 64 < SEQ) {   // prefetch next chunk (drains at next barrier)
            const f16* Kn = Kg + (c0 + 64) * 64;
            const f16* Vn = Vg + (c0 + 64) * 64;
            kr0 = *(const f16x8*)&Kn[krow * 64 + kc8 * 8];
            kr1 = *(const f16x8*)&Kn[(32 + krow) * 64 + kc8 * 8];
            vr0 = *(const f16x8*)&Vn[lane * 64 + w * 16];
            vr1 = *(const f16x8*)&Vn[lane * 64 + w * 16 + 8];
#pragma unroll
            for (int ct = 0; ct < 4; ++ct)
#pragma unroll
                for (int r = 0; r < 4; ++r)
                    mnxt[ct * 4 + r] = Mg[(size_t)r * SEQ + c0 + 64 + ct * 16 + sub];
        }

        // S = Q.K^T
        f32x4 s[4];
#pragma unroll
        for (int ct = 0; ct < 4; ++ct) {
            f16x8 kf0 = *(const f16x8*)&Ks[(ct * 16 + sub) * PIT + quad * 8];
            f16x8 kf1 = *(const f16x8*)&Ks[(ct * 16 + sub) * PIT + 32 + quad * 8];
            f32x4 a = (f32x4){0.f, 0.f, 0.f, 0.f};
            a = __builtin_amdgcn_mfma_f32_16x16x32_f16(qf0, kf0, a, 0, 0, 0);
            a = __builtin_amdgcn_mfma_f32_16x16x32_f16(qf1, kf1, a, 0, 0, 0);
            s[ct] = a;
        }
        // softmax: mask add, row max (16-lane reduce), exp, per-lane partial l
        float mnew[4];
#pragma unroll
        for (int r = 0; r < 4; ++r) mnew[r] = m_run[r];
#pragma unroll
        for (int ct = 0; ct < 4; ++ct)
#pragma unroll
            for (int r = 0; r < 4; ++r) {
                s[ct][r] += (float)mcur[ct * 4 + r];
                mnew[r] = fmaxf(mnew[r], s[ct][r]);
            }
#pragma unroll
        for (int r = 0; r < 4; ++r)
#pragma unroll
            for (int mk = 1; mk < 16; mk <<= 1)
                mnew[r] = fmaxf(mnew[r], __shfl_xor(mnew[r], mk, 64));
        float alpha[4], ps[4];
#pragma unroll
        for (int r = 0; r < 4; ++r) { alpha[r] = __expf(m_run[r] - mnew[r]); ps[r] = 0.f; }
#pragma unroll
        for (int ct = 0; ct < 4; ++ct)
#pragma unroll
            for (int r = 0; r < 4; ++r) {
                float p = __expf(s[ct][r] - mnew[r]);
                s[ct][r] = p;
                ps[r] += p;
            }
#pragma unroll
        for (int r = 0; r < 4; ++r) {
            l_lane[r] = l_lane[r] * alpha[r] + ps[r];
            m_run[r] = mnew[r];
        }
        // P -> LDS (wave-private rows of QP)
#pragma unroll
        for (int ct = 0; ct < 4; ++ct)
#pragma unroll
            for (int r = 0; r < 4; ++r)
                QP[(w * 16 + quad * 4 + r) * PPIT + ct * 16 + sub] = (f16)s[ct][r];
#pragma unroll
        for (int dt = 0; dt < 4; ++dt)
#pragma unroll
            for (int r = 0; r < 4; ++r) o[dt][r] *= alpha[r];
        f16x4 p00 = *(const f16x4*)&QP[(w * 16 + sub) * PPIT + quad * 8];
        f16x4 p01 = *(const f16x4*)&QP[(w * 16 + sub) * PPIT + quad * 8 + 4];
        f16x4 p10 = *(const f16x4*)&QP[(w * 16 + sub) * PPIT + 32 + quad * 8];
        f16x4 p11 = *(const f16x4*)&QP[(w * 16 + sub) * PPIT + 32 + quad * 8 + 4];
        f16x8 pf0 = {p00[0], p00[1], p00[2], p00[3], p01[0], p01[1], p01[2], p01[3]};
        f16x8 pf1 = {p10[0], p10[1], p10[2], p10[3], p11[0], p11[1], p11[2], p11[3]};
#pragma unroll
        for (int dt = 0; dt < 4; ++dt) {
            f16x8 vf0 = *(const f16x8*)&Vt[(dt * 16 + sub) * PIT + quad * 8];
            f16x8 vf1 = *(const f16x8*)&Vt[(dt * 16 + sub) * PIT + 32 + quad * 8];
            o[dt] = __builtin_amdgcn_mfma_f32_16x16x32_f16(pf0, vf0, o[dt], 0, 0, 0);
            o[dt] = __builtin_amdgcn_mfma_f32_16x16x32_f16(pf1, vf1, o[dt], 0, 0, 0);
        }
    }
    // final l reduce (once), epilogue
    float lsc = lscale[h];
#pragma unroll
    for (int r = 0; r < 4; ++r) {
#pragma unroll
        for (int mk = 1; mk < 16; mk <<= 1)
            l_lane[r] += __shfl_xor(l_lane[r], mk, 64);
        float inv = lsc / l_lane[r];
        int q = qb + w * 16 + quad * 4 + r;
#pragma unroll
        for (int dt = 0; dt < 4; ++dt)
            Og[((size_t)n * SEQ + q) * CH + h * 64 + dt * 16 + sub] =
                (f16)(o[dt][r] * inv);
    }
}

// ---------------------------------------------------------------------------
// Output projection, f16 inputs, reg-prefetched staging. fp32 out.
// ---------------------------------------------------------------------------
__global__ __launch_bounds__(256, 3) void out_gemm(const f16* __restrict__ A,
                                                   const f16* __restrict__ Wh,
                                                   const float* __restrict__ bias,
                                                   float* __restrict__ out)
{
    __shared__ f16 As[128 * GP];
    __shared__ f16 Bs[128 * GP];
    const int t    = threadIdx.x;
    const int w    = t >> 6;
    const int lane = t & 63;
    const int quad = lane >> 4;
    const int sub  = lane & 15;
    const int wm   = w & 1, wn = w >> 1;
    const int f0   = blockIdx.x * 128;
    const int m0   = blockIdx.y * 128;
    const int srow = t >> 1;
    const int sk   = (t & 1) * 16;

    const f16* ag = A + (size_t)(m0 + srow) * CH + sk;
    const f16* bg = Wh + (size_t)(f0 + srow) * CH + sk;
    f16x8 a0 = *(const f16x8*)(ag);
    f16x8 a1 = *(const f16x8*)(ag + 8);
    f16x8 b0 = *(const f16x8*)(bg);
    f16x8 b1 = *(const f16x8*)(bg + 8);

    f32x4 acc[4][4];
#pragma unroll
    for (int i = 0; i < 4; ++i)
#pragma unroll
        for (int j = 0; j < 4; ++j) acc[i][j] = (f32x4){0.f, 0.f, 0.f, 0.f};

    for (int k0 = 0; k0 < CH; k0 += 32) {
        __syncthreads();
        *(f16x8*)&As[srow * GP + sk + 0] = a0;
        *(f16x8*)&As[srow * GP + sk + 8] = a1;
        *(f16x8*)&Bs[srow * GP + sk + 0] = b0;
        *(f16x8*)&Bs[srow * GP + sk + 8] = b1;
        __syncthreads();
        if (k0 + 32 < CH) {
            a0 = *(const f16x8*)(ag + k0 + 32);
            a1 = *(const f16x8*)(ag + k0 + 40);
            b0 = *(const f16x8*)(bg + k0 + 32);
            b1 = *(const f16x8*)(bg + k0 + 40);
        }
        f16x8 af[4], bf[4];
#pragma unroll
        for (int i = 0; i < 4; ++i) {
            af[i] = *(const f16x8*)&As[(wm * 64 + i * 16 + sub) * GP + quad * 8];
            bf[i] = *(const f16x8*)&Bs[(wn * 64 + i * 16 + sub) * GP + quad * 8];
        }
#pragma unroll
        for (int i = 0; i < 4; ++i)
#pragma unroll
            for (int j = 0; j < 4; ++j)
                acc[i][j] = __builtin_amdgcn_mfma_f32_16x16x32_f16(af[i], bf[j], acc[i][j], 0, 0, 0);
    }
    float bb[4];
#pragma unroll
    for (int j = 0; j < 4; ++j) bb[j] = bias[f0 + wn * 64 + j * 16 + sub];
#pragma unroll
    for (int i = 0; i < 4; ++i)
#pragma unroll
        for (int r = 0; r < 4; ++r) {
            int m = m0 + wm * 64 + i * 16 + quad * 4 + r;
            float* orow = out + (size_t)m * CH + f0 + wn * 64;
#pragma unroll
            for (int j = 0; j < 4; ++j)
                orow[j * 16 + sub] = acc[i][j][r] + bb[j];
        }
}

extern "C" void kernel_launch(void* const* d_in, const int* in_sizes, int n_in,
                              void* d_out, int out_size, void* d_ws, size_t ws_size,
                              hipStream_t stream) {
    const float* x    = (const float*)d_in[0];
    const float* w1   = (const float*)d_in[1];
    const float* b1   = (const float*)d_in[2];
    const float* ls   = (const float*)d_in[3];
    const float* lrn  = (const float*)d_in[4];
    const float* w2   = (const float*)d_in[5];
    const float* b2   = (const float*)d_in[6];
    const float* msk  = (const float*)d_in[7];
    f16*   ws16 = (f16*)d_ws;
    float* out  = (float*)d_out;

    hipLaunchKernelGGL(cvt_f16, dim3(4096, 4), dim3(256), 0, stream,
                       x, w1, w2, msk,
                       ws16 + XHOFF, ws16 + W1OFF, ws16 + W2OFF, ws16 + MOFF);
    hipLaunchKernelGGL(qkv_gemm, dim3(F3 / 128, (NB * SEQ) / 128), dim3(256), 0, stream,
                       ws16 + XHOFF, ws16 + W1OFF, b1, ls, ws16);
    hipLaunchKernelGGL(attn, dim3(SEQ / 64, NH, NB), dim3(256), 0, stream,
                       ws16, ws16 + QSZ, ws16 + 2 * QSZ, ws16 + MOFF, lrn, ws16 + OATT);
    hipLaunchKernelGGL(out_gemm, dim3(CH / 128, (NB * SEQ) / 128), dim3(256), 0, stream,
                       ws16 + OATT, ws16 + W2OFF, b2, out);
}

// Round 6
// 227.537 us; speedup vs baseline: 5.9205x; 1.0113x over previous
//
#include <hip/hip_runtime.h>
#include <math.h>

// Problem constants
#define NB   2
#define SEQ  2048
#define CH   768
#define NH   12
#define HD   64
#define F3   2304
#define LSMAX 4.605170185988092f
#define LOG2E 1.4426950408889634f

typedef _Float16 f16;
typedef __attribute__((ext_vector_type(8))) _Float16 f16x8;
typedef __attribute__((ext_vector_type(4))) _Float16 f16x4;
typedef __attribute__((ext_vector_type(2))) _Float16 f16x2;
typedef __attribute__((ext_vector_type(4))) float f32x4;

// f16 workspace layout (units: f16 elements)
#define QSZ   3145728                 // per Q/K/V tensor
#define OATT  (3 * QSZ)               // attn out [N,L,C] f16 (3145728)
#define XHOFF 12582912                // x -> f16 (3145728)
#define W1OFF 15728640                // in_proj_w -> f16 (1769472)
#define W2OFF 17498112                // out_proj_w -> f16 (589824)
#define MOFF  18087936                // mask -> f16*LOG2E (4194304)
#define FLAGO 22282240                // int flag: mask nonzero

// LDS pitches
#define PIT  72   // attn K/V tiles: 144B rows, 16B-aligned (b128 ok)
#define PPIT 76   // attn Q/P tile: 152B rows, 8B-aligned (b64 ops only)
#define GP   40   // GEMM tiles: 80B rows, 16B-aligned (b128 ok, bank-floor)

// ---------------------------------------------------------------------------
// One-shot fp32 -> f16 convert of X, W1, W2, mask (mask scaled by LOG2E).
// Also sets *flag=1 if mask has any nonzero (flag pre-zeroed by memset).
// ---------------------------------------------------------------------------
__global__ __launch_bounds__(256) void cvt_f16(const float* __restrict__ X,
                                               const float* __restrict__ W1,
                                               const float* __restrict__ W2,
                                               const float* __restrict__ M,
                                               f16* __restrict__ Xh,
                                               f16* __restrict__ W1h,
                                               f16* __restrict__ W2h,
                                               f16* __restrict__ Mh,
                                               int* __restrict__ flag)
{
    int tid = blockIdx.x * 256 + threadIdx.x;
    const float* src; f16* dst; int n4;
    switch (blockIdx.y) {
        case 0:  src = X;  dst = Xh;  n4 = 786432;  break;
        case 1:  src = W1; dst = W1h; n4 = 442368;  break;
        case 2:  src = W2; dst = W2h; n4 = 147456;  break;
        default: src = M;  dst = Mh;  n4 = 1048576; break;
    }
    if (tid < n4) {
        float4 v = ((const float4*)src)[tid];
        if (blockIdx.y == 3) {
            bool nz = (v.x != 0.f) || (v.y != 0.f) || (v.z != 0.f) || (v.w != 0.f);
            if (__any(nz) && (threadIdx.x & 63) == 0) atomicOr(flag, 1);
            v.x *= LOG2E; v.y *= LOG2E; v.z *= LOG2E; v.w *= LOG2E;
        }
        f16x4 o = {(f16)v.x, (f16)v.y, (f16)v.z, (f16)v.w};
        ((f16x4*)dst)[tid] = o;
    }
}

// ---------------------------------------------------------------------------
// QKV GEMM, f16 inputs, reg-prefetched staging. 128x128 tile, 4 waves 2x2,
// BK=32, 16x16x32 MFMA. Epilogue: bias, l2-norm Q/K rows, fold ls*LOG2E
// into Q (log2-domain softmax downstream).
// ---------------------------------------------------------------------------
__global__ __launch_bounds__(256, 3) void qkv_gemm(const f16* __restrict__ Xh,
                                                   const f16* __restrict__ Wh,
                                                   const float* __restrict__ bias,
                                                   const float* __restrict__ logit_scale,
                                                   f16* __restrict__ qkv16)
{
    __shared__ f16 As[128 * GP];
    __shared__ f16 Bs[128 * GP];
    const int t    = threadIdx.x;
    const int w    = t >> 6;
    const int lane = t & 63;
    const int quad = lane >> 4;
    const int sub  = lane & 15;
    const int wm   = w & 1, wn = w >> 1;
    const int f0   = blockIdx.x * 128;
    const int m0   = blockIdx.y * 128;
    const int srow = t >> 1;
    const int sk   = (t & 1) * 16;

    const f16* ag = Xh + (size_t)(m0 + srow) * CH + sk;
    const f16* bg = Wh + (size_t)(f0 + srow) * CH + sk;
    f16x8 a0 = *(const f16x8*)(ag);
    f16x8 a1 = *(const f16x8*)(ag + 8);
    f16x8 b0 = *(const f16x8*)(bg);
    f16x8 b1 = *(const f16x8*)(bg + 8);

    f32x4 acc[4][4];
#pragma unroll
    for (int i = 0; i < 4; ++i)
#pragma unroll
        for (int j = 0; j < 4; ++j) acc[i][j] = (f32x4){0.f, 0.f, 0.f, 0.f};

    for (int k0 = 0; k0 < CH; k0 += 32) {
        __syncthreads();
        *(f16x8*)&As[srow * GP + sk + 0] = a0;
        *(f16x8*)&As[srow * GP + sk + 8] = a1;
        *(f16x8*)&Bs[srow * GP + sk + 0] = b0;
        *(f16x8*)&Bs[srow * GP + sk + 8] = b1;
        __syncthreads();
        if (k0 + 32 < CH) {
            a0 = *(const f16x8*)(ag + k0 + 32);
            a1 = *(const f16x8*)(ag + k0 + 40);
            b0 = *(const f16x8*)(bg + k0 + 32);
            b1 = *(const f16x8*)(bg + k0 + 40);
        }
        f16x8 af[4], bf[4];
#pragma unroll
        for (int i = 0; i < 4; ++i) {
            af[i] = *(const f16x8*)&As[(wm * 64 + i * 16 + sub) * GP + quad * 8];
            bf[i] = *(const f16x8*)&Bs[(wn * 64 + i * 16 + sub) * GP + quad * 8];
        }
#pragma unroll
        for (int i = 0; i < 4; ++i)
#pragma unroll
            for (int j = 0; j < 4; ++j)
                acc[i][j] = __builtin_amdgcn_mfma_f32_16x16x32_f16(af[i], bf[j], acc[i][j], 0, 0, 0);
    }

    const int t3 = f0 / CH;                       // 0=q,1=k,2=v (block-uniform)
    const int h  = ((f0 + wn * 64) % CH) >> 6;    // wave-uniform head
    f16* dst = qkv16 + (size_t)t3 * QSZ;
    float lsv = (t3 == 0) ? __expf(fminf(logit_scale[h], LSMAX)) * LOG2E : 1.0f;
    float bb[4];
#pragma unroll
    for (int j = 0; j < 4; ++j) bb[j] = bias[f0 + wn * 64 + j * 16 + sub];
#pragma unroll
    for (int i = 0; i < 4; ++i) {
#pragma unroll
        for (int r = 0; r < 4; ++r) {
            int m = m0 + wm * 64 + i * 16 + quad * 4 + r;
            int n = m >> 11, l = m & 2047;
            float v[4];
#pragma unroll
            for (int j = 0; j < 4; ++j) v[j] = acc[i][j][r] + bb[j];
            float scale = 1.0f;
            if (t3 < 2) {
                float ss = v[0] * v[0] + v[1] * v[1] + v[2] * v[2] + v[3] * v[3];
#pragma unroll
                for (int mk = 1; mk < 16; mk <<= 1) ss += __shfl_xor(ss, mk, 64);
                scale = 1.0f / fmaxf(sqrtf(ss), 1e-12f);
                if (t3 == 0) scale *= lsv;
            }
            f16* drow = dst + (((size_t)n * NH + h) * SEQ + l) * HD;
#pragma unroll
            for (int j = 0; j < 4; ++j)
                drow[j * 16 + sub] = (f16)(v[j] * scale);
        }
    }
}

// ---------------------------------------------------------------------------
// Flash attention, f16 MFMA, log2-domain softmax, double-buffered K/V LDS
// (1 barrier per chunk), l via ones-column MFMA, packed-f16 max reduce,
// mask skipped entirely when *flag==0.
// ---------------------------------------------------------------------------
__global__ __launch_bounds__(256, 3) void attn(const f16* __restrict__ Qh,
                                               const f16* __restrict__ Kh,
                                               const f16* __restrict__ Vh,
                                               const f16* __restrict__ Mh,
                                               const float* __restrict__ lscale,
                                               const int* __restrict__ flag,
                                               f16* __restrict__ Og)
{
    __shared__ f16 Ks[2][64 * PIT];
    __shared__ f16 Vt[2][64 * PIT];
    __shared__ f16 QP[64 * PPIT];   // Q tile, then reused as P tile

    const int t    = threadIdx.x;
    const int w    = t >> 6;
    const int lane = t & 63;
    const int quad = lane >> 4;
    const int sub  = lane & 15;
    const int qb   = blockIdx.x * 64;
    const int h    = blockIdx.y, n = blockIdx.z;
    const bool has_mask = (*flag) != 0;

    const f16* Qg = Qh + ((size_t)(n * NH + h) * SEQ + qb) * HD;
    const f16* Kg = Kh + (size_t)(n * NH + h) * SEQ * HD;
    const f16* Vg = Vh + (size_t)(n * NH + h) * SEQ * HD;
    const f16* Mg = Mh + (size_t)(qb + w * 16 + quad * 4) * SEQ;

    // stage Q (b128 global loads, b64 LDS stores: PPIT rows 8B-aligned)
#pragma unroll
    for (int rep = 0; rep < 2; ++rep) {
        int id = rep * 256 + t;
        int row = id >> 3, c8 = id & 7;
        f16x8 v = *(const f16x8*)&Qg[row * 64 + c8 * 8];
        *(f16x4*)&QP[row * PPIT + c8 * 8 + 0] = (f16x4){v[0], v[1], v[2], v[3]};
        *(f16x4*)&QP[row * PPIT + c8 * 8 + 4] = (f16x4){v[4], v[5], v[6], v[7]};
    }

    // prefetch chunk 0: K (2 b128), V (2 b128), mask (16 f16, slow path only)
    const int krow = t >> 3, kc8 = t & 7;
    f16x8 kr0 = *(const f16x8*)&Kg[krow * 64 + kc8 * 8];
    f16x8 kr1 = *(const f16x8*)&Kg[(32 + krow) * 64 + kc8 * 8];
    f16x8 vr0 = *(const f16x8*)&Vg[lane * 64 + w * 16];
    f16x8 vr1 = *(const f16x8*)&Vg[lane * 64 + w * 16 + 8];
    f16 mnxt[16];
    if (has_mask) {
#pragma unroll
        for (int ct = 0; ct < 4; ++ct)
#pragma unroll
            for (int r = 0; r < 4; ++r)
                mnxt[ct * 4 + r] = Mg[(size_t)r * SEQ + ct * 16 + sub];
    }

    __syncthreads();   // Q staged
    f16x8 qf0, qf1;
    {
        f16x4 l0 = *(const f16x4*)&QP[(w * 16 + sub) * PPIT + quad * 8];
        f16x4 l1 = *(const f16x4*)&QP[(w * 16 + sub) * PPIT + quad * 8 + 4];
        f16x4 l2 = *(const f16x4*)&QP[(w * 16 + sub) * PPIT + 32 + quad * 8];
        f16x4 l3 = *(const f16x4*)&QP[(w * 16 + sub) * PPIT + 32 + quad * 8 + 4];
        qf0 = (f16x8){l0[0], l0[1], l0[2], l0[3], l1[0], l1[1], l1[2], l1[3]};
        qf1 = (f16x8){l2[0], l2[1], l2[2], l2[3], l3[0], l3[1], l3[2], l3[3]};
    }

    // store chunk 0 into buffer 0; prefetch chunk 1
    *(f16x8*)&Ks[0][krow * PIT + kc8 * 8] = kr0;
    *(f16x8*)&Ks[0][(32 + krow) * PIT + kc8 * 8] = kr1;
#pragma unroll
    for (int j = 0; j < 8; ++j) {
        Vt[0][(w * 16 + j) * PIT + lane] = vr0[j];
        Vt[0][(w * 16 + 8 + j) * PIT + lane] = vr1[j];
    }
    {
        const f16* Kn = Kg + 64 * 64;
        const f16* Vn = Vg + 64 * 64;
        kr0 = *(const f16x8*)&Kn[krow * 64 + kc8 * 8];
        kr1 = *(const f16x8*)&Kn[(32 + krow) * 64 + kc8 * 8];
        vr0 = *(const f16x8*)&Vn[lane * 64 + w * 16];
        vr1 = *(const f16x8*)&Vn[lane * 64 + w * 16 + 8];
    }

    const f16x8 ones = {(f16)1.f, (f16)1.f, (f16)1.f, (f16)1.f,
                        (f16)1.f, (f16)1.f, (f16)1.f, (f16)1.f};
    f32x4 o[4];
    f32x4 l_acc = (f32x4){0.f, 0.f, 0.f, 0.f};
    float m_run[4];
#pragma unroll
    for (int dt = 0; dt < 4; ++dt) o[dt] = (f32x4){0.f, 0.f, 0.f, 0.f};
#pragma unroll
    for (int r = 0; r < 4; ++r) m_run[r] = -1e30f;

    const int NC = SEQ / 64;
    for (int c = 0; c < NC; ++c) {
        __syncthreads();   // prev reads of buf done; this chunk's buf visible
        const int cur = c & 1, nxt = cur ^ 1;
        if (c + 1 < NC) {  // store prefetched chunk c+1 into the other buffer
            *(f16x8*)&Ks[nxt][krow * PIT + kc8 * 8] = kr0;
            *(f16x8*)&Ks[nxt][(32 + krow) * PIT + kc8 * 8] = kr1;
#pragma unroll
            for (int j = 0; j < 8; ++j) {
                Vt[nxt][(w * 16 + j) * PIT + lane] = vr0[j];
                Vt[nxt][(w * 16 + 8 + j) * PIT + lane] = vr1[j];
            }
            if (c + 2 < NC) {   // prefetch chunk c+2
                const f16* Kn = Kg + (c + 2) * 64 * 64;
                const f16* Vn = Vg + (c + 2) * 64 * 64;
                kr0 = *(const f16x8*)&Kn[krow * 64 + kc8 * 8];
                kr1 = *(const f16x8*)&Kn[(32 + krow) * 64 + kc8 * 8];
                vr0 = *(const f16x8*)&Vn[lane * 64 + w * 16];
                vr1 = *(const f16x8*)&Vn[lane * 64 + w * 16 + 8];
            }
        }
        f16 mcur[16];
        if (has_mask) {
#pragma unroll
            for (int i = 0; i < 16; ++i) mcur[i] = mnxt[i];
            if (c + 1 < NC) {
#pragma unroll
                for (int ct = 0; ct < 4; ++ct)
#pragma unroll
                    for (int r = 0; r < 4; ++r)
                        mnxt[ct * 4 + r] = Mg[(size_t)r * SEQ + (c + 1) * 64 + ct * 16 + sub];
            }
        }

        // S = Q.K^T (log2 domain: ls*log2e folded into Q)
        f32x4 s[4];
#pragma unroll
        for (int ct = 0; ct < 4; ++ct) {
            f16x8 kf0 = *(const f16x8*)&Ks[cur][(ct * 16 + sub) * PIT + quad * 8];
            f16x8 kf1 = *(const f16x8*)&Ks[cur][(ct * 16 + sub) * PIT + 32 + quad * 8];
            f32x4 a = (f32x4){0.f, 0.f, 0.f, 0.f};
            a = __builtin_amdgcn_mfma_f32_16x16x32_f16(qf0, kf0, a, 0, 0, 0);
            a = __builtin_amdgcn_mfma_f32_16x16x32_f16(qf1, kf1, a, 0, 0, 0);
            s[ct] = a;
        }
        if (has_mask) {
#pragma unroll
            for (int ct = 0; ct < 4; ++ct)
#pragma unroll
                for (int r = 0; r < 4; ++r)
                    s[ct][r] += (float)mcur[ct * 4 + r];
        }
        // row max: local f32 tree, then packed-f16 16-lane butterfly
        float mnew[4];
#pragma unroll
        for (int r = 0; r < 4; ++r)
            mnew[r] = fmaxf(fmaxf(fmaxf(s[0][r], s[1][r]), fmaxf(s[2][r], s[3][r])), m_run[r]);
        {
            union { f16x2 h; int i; } p0, p1, v0, v1;
            p0.h = (f16x2){(f16)mnew[0], (f16)mnew[1]};
            p1.h = (f16x2){(f16)mnew[2], (f16)mnew[3]};
#pragma unroll
            for (int mk = 1; mk < 16; mk <<= 1) {
                v0.i = __shfl_xor(p0.i, mk, 64);
                v1.i = __shfl_xor(p1.i, mk, 64);
                p0.h = __builtin_elementwise_max(p0.h, v0.h);
                p1.h = __builtin_elementwise_max(p1.h, v1.h);
            }
            mnew[0] = (float)p0.h[0]; mnew[1] = (float)p0.h[1];
            mnew[2] = (float)p1.h[0]; mnew[3] = (float)p1.h[1];
        }
        float alpha[4];
#pragma unroll
        for (int r = 0; r < 4; ++r) {
            alpha[r] = exp2f(m_run[r] - mnew[r]);
            m_run[r] = mnew[r];
        }
        // P = exp2(S - M) -> LDS f16 (wave-private rows)
#pragma unroll
        for (int ct = 0; ct < 4; ++ct)
#pragma unroll
            for (int r = 0; r < 4; ++r) {
                float p = exp2f(s[ct][r] - mnew[r]);
                QP[(w * 16 + quad * 4 + r) * PPIT + ct * 16 + sub] = (f16)p;
            }
        // rescale O and l
#pragma unroll
        for (int dt = 0; dt < 4; ++dt)
#pragma unroll
            for (int r = 0; r < 4; ++r) o[dt][r] *= alpha[r];
#pragma unroll
        for (int r = 0; r < 4; ++r) l_acc[r] *= alpha[r];
        // P fragments (b64 pairs; rows wave-private, same-wave DS in order)
        f16x4 p00 = *(const f16x4*)&QP[(w * 16 + sub) * PPIT + quad * 8];
        f16x4 p01 = *(const f16x4*)&QP[(w * 16 + sub) * PPIT + quad * 8 + 4];
        f16x4 p10 = *(const f16x4*)&QP[(w * 16 + sub) * PPIT + 32 + quad * 8];
        f16x4 p11 = *(const f16x4*)&QP[(w * 16 + sub) * PPIT + 32 + quad * 8 + 4];
        f16x8 pf0 = {p00[0], p00[1], p00[2], p00[3], p01[0], p01[1], p01[2], p01[3]};
        f16x8 pf1 = {p10[0], p10[1], p10[2], p10[3], p11[0], p11[1], p11[2], p11[3]};
        // l += P.1 (row sums via MFMA)
        l_acc = __builtin_amdgcn_mfma_f32_16x16x32_f16(pf0, ones, l_acc, 0, 0, 0);
        l_acc = __builtin_amdgcn_mfma_f32_16x16x32_f16(pf1, ones, l_acc, 0, 0, 0);
        // O += P.V
#pragma unroll
        for (int dt = 0; dt < 4; ++dt) {
            f16x8 vf0 = *(const f16x8*)&Vt[cur][(dt * 16 + sub) * PIT + quad * 8];
            f16x8 vf1 = *(const f16x8*)&Vt[cur][(dt * 16 + sub) * PIT + 32 + quad * 8];
            o[dt] = __builtin_amdgcn_mfma_f32_16x16x32_f16(pf0, vf0, o[dt], 0, 0, 0);
            o[dt] = __builtin_amdgcn_mfma_f32_16x16x32_f16(pf1, vf1, o[dt], 0, 0, 0);
        }
    }
    // epilogue: * learned_scale / l  (l_acc identical across sub lanes)
    float lsc = lscale[h];
#pragma unroll
    for (int r = 0; r < 4; ++r) {
        float inv = lsc / l_acc[r];
        int q = qb + w * 16 + quad * 4 + r;
#pragma unroll
        for (int dt = 0; dt < 4; ++dt)
            Og[((size_t)n * SEQ + q) * CH + h * 64 + dt * 16 + sub] =
                (f16)(o[dt][r] * inv);
    }
}

// ---------------------------------------------------------------------------
// Output projection, f16 inputs, reg-prefetched staging. fp32 out.
// ---------------------------------------------------------------------------
__global__ __launch_bounds__(256, 3) void out_gemm(const f16* __restrict__ A,
                                                   const f16* __restrict__ Wh,
                                                   const float* __restrict__ bias,
                                                   float* __restrict__ out)
{
    __shared__ f16 As[128 * GP];
    __shared__ f16 Bs[128 * GP];
    const int t    = threadIdx.x;
    const int w    = t >> 6;
    const int lane = t & 63;
    const int quad = lane >> 4;
    const int sub  = lane & 15;
    const int wm   = w & 1, wn = w >> 1;
    const int f0   = blockIdx.x * 128;
    const int m0   = blockIdx.y * 128;
    const int srow = t >> 1;
    const int sk   = (t & 1) * 16;

    const f16* ag = A + (size_t)(m0 + srow) * CH + sk;
    const f16* bg = Wh + (size_t)(f0 + srow) * CH + sk;
    f16x8 a0 = *(const f16x8*)(ag);
    f16x8 a1 = *(const f16x8*)(ag + 8);
    f16x8 b0 = *(const f16x8*)(bg);
    f16x8 b1 = *(const f16x8*)(bg + 8);

    f32x4 acc[4][4];
#pragma unroll
    for (int i = 0; i < 4; ++i)
#pragma unroll
        for (int j = 0; j < 4; ++j) acc[i][j] = (f32x4){0.f, 0.f, 0.f, 0.f};

    for (int k0 = 0; k0 < CH; k0 += 32) {
        __syncthreads();
        *(f16x8*)&As[srow * GP + sk + 0] = a0;
        *(f16x8*)&As[srow * GP + sk + 8] = a1;
        *(f16x8*)&Bs[srow * GP + sk + 0] = b0;
        *(f16x8*)&Bs[srow * GP + sk + 8] = b1;
        __syncthreads();
        if (k0 + 32 < CH) {
            a0 = *(const f16x8*)(ag + k0 + 32);
            a1 = *(const f16x8*)(ag + k0 + 40);
            b0 = *(const f16x8*)(bg + k0 + 32);
            b1 = *(const f16x8*)(bg + k0 + 40);
        }
        f16x8 af[4], bf[4];
#pragma unroll
        for (int i = 0; i < 4; ++i) {
            af[i] = *(const f16x8*)&As[(wm * 64 + i * 16 + sub) * GP + quad * 8];
            bf[i] = *(const f16x8*)&Bs[(wn * 64 + i * 16 + sub) * GP + quad * 8];
        }
#pragma unroll
        for (int i = 0; i < 4; ++i)
#pragma unroll
            for (int j = 0; j < 4; ++j)
                acc[i][j] = __builtin_amdgcn_mfma_f32_16x16x32_f16(af[i], bf[j], acc[i][j], 0, 0, 0);
    }
    float bb[4];
#pragma unroll
    for (int j = 0; j < 4; ++j) bb[j] = bias[f0 + wn * 64 + j * 16 + sub];
#pragma unroll
    for (int i = 0; i < 4; ++i)
#pragma unroll
        for (int r = 0; r < 4; ++r) {
            int m = m0 + wm * 64 + i * 16 + quad * 4 + r;
            float* orow = out + (size_t)m * CH + f0 + wn * 64;
#pragma unroll
            for (int j = 0; j < 4; ++j)
                orow[j * 16 + sub] = acc[i][j][r] + bb[j];
        }
}

extern "C" void kernel_launch(void* const* d_in, const int* in_sizes, int n_in,
                              void* d_out, int out_size, void* d_ws, size_t ws_size,
                              hipStream_t stream) {
    const float* x    = (const float*)d_in[0];
    const float* w1   = (const float*)d_in[1];
    const float* b1   = (const float*)d_in[2];
    const float* ls   = (const float*)d_in[3];
    const float* lrn  = (const float*)d_in[4];
    const float* w2   = (const float*)d_in[5];
    const float* b2   = (const float*)d_in[6];
    const float* msk  = (const float*)d_in[7];
    f16*   ws16 = (f16*)d_ws;
    int*   flag = (int*)(ws16 + FLAGO);
    float* out  = (float*)d_out;

    (void)hipMemsetAsync(flag, 0, 4, stream);
    hipLaunchKernelGGL(cvt_f16, dim3(4096, 4), dim3(256), 0, stream,
                       x, w1, w2, msk,
                       ws16 + XHOFF, ws16 + W1OFF, ws16 + W2OFF, ws16 + MOFF, flag);
    hipLaunchKernelGGL(qkv_gemm, dim3(F3 / 128, (NB * SEQ) / 128), dim3(256), 0, stream,
                       ws16 + XHOFF, ws16 + W1OFF, b1, ls, ws16);
    hipLaunchKernelGGL(attn, dim3(SEQ / 64, NH, NB), dim3(256), 0, stream,
                       ws16, ws16 + QSZ, ws16 + 2 * QSZ, ws16 + MOFF, lrn, flag,
                       ws16 + OATT);
    hipLaunchKernelGGL(out_gemm, dim3(CH / 128, (NB * SEQ) / 128), dim3(256), 0, stream,
                       ws16 + OATT, ws16 + W2OFF, b2, out);
}

// Round 7
// 212.037 us; speedup vs baseline: 6.3533x; 1.0731x over previous
//
#include <hip/hip_runtime.h>
#include <math.h>

// Problem constants
#define NB   2
#define SEQ  2048
#define CH   768
#define NH   12
#define HD   64
#define F3   2304
#define LSMAX 4.605170185988092f
#define LOG2E 1.4426950408889634f

typedef _Float16 f16;
typedef __attribute__((ext_vector_type(8))) _Float16 f16x8;
typedef __attribute__((ext_vector_type(4))) _Float16 f16x4;
typedef __attribute__((ext_vector_type(2))) _Float16 f16x2;
typedef __attribute__((ext_vector_type(4))) float f32x4;

// f16 workspace layout (units: f16 elements)
#define QSZ   3145728                 // per Q/K/V tensor
#define OATT  (3 * QSZ)               // attn out [N,L,C] f16 (3145728)
#define XHOFF 12582912                // x -> f16 (3145728)
#define W1OFF 15728640                // in_proj_w -> f16 (1769472)
#define W2OFF 17498112                // out_proj_w -> f16 (589824)
#define FLAGO 18087936                // int flag: mask nonzero

// LDS pitches
#define KP   72    // attn K tile: 144B rows, 16B-aligned b128
#define VP   136   // attn Vt tile (128 keys): 272B rows, 16B-aligned b128
#define PPIT 76    // attn Q/P tile: 152B rows, b64 frag reads
#define GP   40    // GEMM tiles: 80B rows, 16B-aligned b128

// ---------------------------------------------------------------------------
// fp32 -> f16 convert of X, W1, W2; mask is scanned for nonzero only.
// ---------------------------------------------------------------------------
__global__ __launch_bounds__(256) void cvt_f16(const float* __restrict__ X,
                                               const float* __restrict__ W1,
                                               const float* __restrict__ W2,
                                               const float* __restrict__ M,
                                               f16* __restrict__ Xh,
                                               f16* __restrict__ W1h,
                                               f16* __restrict__ W2h,
                                               int* __restrict__ flag)
{
    int tid = blockIdx.x * 256 + threadIdx.x;
    if (blockIdx.y == 3) {   // mask: flag-only scan
        if (tid < 1048576) {
            float4 v = ((const float4*)M)[tid];
            bool nz = (v.x != 0.f) || (v.y != 0.f) || (v.z != 0.f) || (v.w != 0.f);
            if (__any(nz) && (threadIdx.x & 63) == 0) atomicOr(flag, 1);
        }
        return;
    }
    const float* src; f16* dst; int n4;
    switch (blockIdx.y) {
        case 0:  src = X;  dst = Xh;  n4 = 786432;  break;
        case 1:  src = W1; dst = W1h; n4 = 442368;  break;
        default: src = W2; dst = W2h; n4 = 147456;  break;
    }
    if (tid < n4) {
        float4 v = ((const float4*)src)[tid];
        f16x4 o = {(f16)v.x, (f16)v.y, (f16)v.z, (f16)v.w};
        ((f16x4*)dst)[tid] = o;
    }
}

// ---------------------------------------------------------------------------
// QKV GEMM, f16 inputs, reg-prefetched staging. 128x128 tile, 4 waves 2x2,
// BK=32. Epilogue: bias, l2-norm Q/K rows, fold exp(min(ls,MAX))*LOG2E into Q.
// ---------------------------------------------------------------------------
__global__ __launch_bounds__(256, 3) void qkv_gemm(const f16* __restrict__ Xh,
                                                   const f16* __restrict__ Wh,
                                                   const float* __restrict__ bias,
                                                   const float* __restrict__ logit_scale,
                                                   f16* __restrict__ qkv16)
{
    __shared__ f16 As[128 * GP];
    __shared__ f16 Bs[128 * GP];
    const int t    = threadIdx.x;
    const int w    = t >> 6;
    const int lane = t & 63;
    const int quad = lane >> 4;
    const int sub  = lane & 15;
    const int wm   = w & 1, wn = w >> 1;
    const int f0   = blockIdx.x * 128;
    const int m0   = blockIdx.y * 128;
    const int srow = t >> 1;
    const int sk   = (t & 1) * 16;

    const f16* ag = Xh + (size_t)(m0 + srow) * CH + sk;
    const f16* bg = Wh + (size_t)(f0 + srow) * CH + sk;
    f16x8 a0 = *(const f16x8*)(ag);
    f16x8 a1 = *(const f16x8*)(ag + 8);
    f16x8 b0 = *(const f16x8*)(bg);
    f16x8 b1 = *(const f16x8*)(bg + 8);

    f32x4 acc[4][4];
#pragma unroll
    for (int i = 0; i < 4; ++i)
#pragma unroll
        for (int j = 0; j < 4; ++j) acc[i][j] = (f32x4){0.f, 0.f, 0.f, 0.f};

    for (int k0 = 0; k0 < CH; k0 += 32) {
        __syncthreads();
        *(f16x8*)&As[srow * GP + sk + 0] = a0;
        *(f16x8*)&As[srow * GP + sk + 8] = a1;
        *(f16x8*)&Bs[srow * GP + sk + 0] = b0;
        *(f16x8*)&Bs[srow * GP + sk + 8] = b1;
        __syncthreads();
        if (k0 + 32 < CH) {
            a0 = *(const f16x8*)(ag + k0 + 32);
            a1 = *(const f16x8*)(ag + k0 + 40);
            b0 = *(const f16x8*)(bg + k0 + 32);
            b1 = *(const f16x8*)(bg + k0 + 40);
        }
        f16x8 af[4], bf[4];
#pragma unroll
        for (int i = 0; i < 4; ++i) {
            af[i] = *(const f16x8*)&As[(wm * 64 + i * 16 + sub) * GP + quad * 8];
            bf[i] = *(const f16x8*)&Bs[(wn * 64 + i * 16 + sub) * GP + quad * 8];
        }
#pragma unroll
        for (int i = 0; i < 4; ++i)
#pragma unroll
            for (int j = 0; j < 4; ++j)
                acc[i][j] = __builtin_amdgcn_mfma_f32_16x16x32_f16(af[i], bf[j], acc[i][j], 0, 0, 0);
    }

    const int t3 = f0 / CH;
    const int h  = ((f0 + wn * 64) % CH) >> 6;
    f16* dst = qkv16 + (size_t)t3 * QSZ;
    float lsv = (t3 == 0) ? __expf(fminf(logit_scale[h], LSMAX)) * LOG2E : 1.0f;
    float bb[4];
#pragma unroll
    for (int j = 0; j < 4; ++j) bb[j] = bias[f0 + wn * 64 + j * 16 + sub];
#pragma unroll
    for (int i = 0; i < 4; ++i) {
#pragma unroll
        for (int r = 0; r < 4; ++r) {
            int m = m0 + wm * 64 + i * 16 + quad * 4 + r;
            int n = m >> 11, l = m & 2047;
            float v[4];
#pragma unroll
            for (int j = 0; j < 4; ++j) v[j] = acc[i][j][r] + bb[j];
            float scale = 1.0f;
            if (t3 < 2) {
                float ss = v[0] * v[0] + v[1] * v[1] + v[2] * v[2] + v[3] * v[3];
#pragma unroll
                for (int mk = 1; mk < 16; mk <<= 1) ss += __shfl_xor(ss, mk, 64);
                scale = 1.0f / fmaxf(sqrtf(ss), 1e-12f);
                if (t3 == 0) scale *= lsv;
            }
            f16* drow = dst + (((size_t)n * NH + h) * SEQ + l) * HD;
#pragma unroll
            for (int j = 0; j < 4; ++j)
                drow[j * 16 + sub] = (f16)(v[j] * scale);
        }
    }
}

// ---------------------------------------------------------------------------
// Flash attention, f16 MFMA, KC=128 keys per iteration (16 iters), log2-domain
// softmax, single-buffer K/V + full register prefetch, P processed in two
// 64-key halves through one shared Q/P tile, l via ones-MFMA.
// ---------------------------------------------------------------------------
__global__ __launch_bounds__(256, 3) void attn(const f16* __restrict__ Qh,
                                               const f16* __restrict__ Kh,
                                               const f16* __restrict__ Vh,
                                               const float* __restrict__ M32,
                                               const float* __restrict__ lscale,
                                               const int* __restrict__ flag,
                                               f16* __restrict__ Og)
{
    __shared__ f16 Ks[128 * KP];    // [key][d]          18.4 KB
    __shared__ f16 Vt[64 * VP];     // [d][key 0..127]   17.4 KB
    __shared__ f16 QP[64 * PPIT];   // Q tile -> P tile   9.7 KB

    const int t    = threadIdx.x;
    const int w    = t >> 6;
    const int lane = t & 63;
    const int quad = lane >> 4;
    const int sub  = lane & 15;
    const int qb   = blockIdx.x * 64;
    const int h    = blockIdx.y, n = blockIdx.z;
    const bool has_mask = (*flag) != 0;

    const f16* Qg = Qh + ((size_t)(n * NH + h) * SEQ + qb) * HD;
    const f16* Kg = Kh + (size_t)(n * NH + h) * SEQ * HD;
    const f16* Vg = Vh + (size_t)(n * NH + h) * SEQ * HD;
    const float* Mg = M32 + (size_t)(qb + w * 16 + quad * 4) * SEQ;

    // stage Q
#pragma unroll
    for (int rep = 0; rep < 2; ++rep) {
        int id = rep * 256 + t;
        int row = id >> 3, c8 = id & 7;
        f16x8 v = *(const f16x8*)&Qg[row * 64 + c8 * 8];
        *(f16x4*)&QP[row * PPIT + c8 * 8 + 0] = (f16x4){v[0], v[1], v[2], v[3]};
        *(f16x4*)&QP[row * PPIT + c8 * 8 + 4] = (f16x4){v[4], v[5], v[6], v[7]};
    }

    // prefetch chunk 0: K 4 b128 (row t>>1, colblock (t&1)*32),
    //                   V 4 b128 (keys 2*lane, 2*lane+1; d-slice w*16..+16)
    const int krow = t >> 1;
    const int kcb  = (t & 1) * 32;
    f16x8 kr0, kr1, kr2, kr3, vr0, vr1, vr2, vr3;
    {
        const f16* kp = Kg + krow * 64 + kcb;
        kr0 = *(const f16x8*)(kp + 0);
        kr1 = *(const f16x8*)(kp + 8);
        kr2 = *(const f16x8*)(kp + 16);
        kr3 = *(const f16x8*)(kp + 24);
        const f16* vp = Vg + (2 * lane) * 64 + w * 16;
        vr0 = *(const f16x8*)(vp + 0);
        vr1 = *(const f16x8*)(vp + 8);
        vr2 = *(const f16x8*)(vp + 64);
        vr3 = *(const f16x8*)(vp + 72);
    }

    __syncthreads();   // Q staged
    f16x8 qf0, qf1;
    {
        f16x4 l0 = *(const f16x4*)&QP[(w * 16 + sub) * PPIT + quad * 8];
        f16x4 l1 = *(const f16x4*)&QP[(w * 16 + sub) * PPIT + quad * 8 + 4];
        f16x4 l2 = *(const f16x4*)&QP[(w * 16 + sub) * PPIT + 32 + quad * 8];
        f16x4 l3 = *(const f16x4*)&QP[(w * 16 + sub) * PPIT + 32 + quad * 8 + 4];
        qf0 = (f16x8){l0[0], l0[1], l0[2], l0[3], l1[0], l1[1], l1[2], l1[3]};
        qf1 = (f16x8){l2[0], l2[1], l2[2], l2[3], l3[0], l3[1], l3[2], l3[3]};
    }

    // store chunk 0 into LDS
    {
        f16* kd = &Ks[krow * KP + kcb];
        *(f16x8*)(kd + 0)  = kr0;
        *(f16x8*)(kd + 8)  = kr1;
        *(f16x8*)(kd + 16) = kr2;
        *(f16x8*)(kd + 24) = kr3;
#pragma unroll
        for (int j = 0; j < 8; ++j) {
            *(f16x2*)&Vt[(w * 16 + j) * VP + 2 * lane]     = (f16x2){vr0[j], vr2[j]};
            *(f16x2*)&Vt[(w * 16 + 8 + j) * VP + 2 * lane] = (f16x2){vr1[j], vr3[j]};
        }
    }
    __syncthreads();

    const f16x8 ones = {(f16)1.f, (f16)1.f, (f16)1.f, (f16)1.f,
                        (f16)1.f, (f16)1.f, (f16)1.f, (f16)1.f};
    f32x4 o[4];
    f32x4 l_acc = (f32x4){0.f, 0.f, 0.f, 0.f};
    float m_run[4];
#pragma unroll
    for (int dt = 0; dt < 4; ++dt) o[dt] = (f32x4){0.f, 0.f, 0.f, 0.f};
#pragma unroll
    for (int r = 0; r < 4; ++r) m_run[r] = -1e30f;

    const int NITER = SEQ / 128;
    for (int c = 0; c < NITER; ++c) {
        const int c0 = c * 128;
        // prefetch next chunk (fully overlapped with compute below)
        if (c + 1 < NITER) {
            const f16* kp = Kg + (c0 + 128 + krow) * 64 + kcb;
            kr0 = *(const f16x8*)(kp + 0);
            kr1 = *(const f16x8*)(kp + 8);
            kr2 = *(const f16x8*)(kp + 16);
            kr3 = *(const f16x8*)(kp + 24);
            const f16* vp = Vg + (c0 + 128 + 2 * lane) * 64 + w * 16;
            vr0 = *(const f16x8*)(vp + 0);
            vr1 = *(const f16x8*)(vp + 8);
            vr2 = *(const f16x8*)(vp + 64);
            vr3 = *(const f16x8*)(vp + 72);
        }

        // S = Q.K^T over 128 keys (8 column tiles)
        f32x4 s[8];
#pragma unroll
        for (int ct = 0; ct < 8; ++ct) {
            f16x8 kf0 = *(const f16x8*)&Ks[(ct * 16 + sub) * KP + quad * 8];
            f16x8 kf1 = *(const f16x8*)&Ks[(ct * 16 + sub) * KP + 32 + quad * 8];
            f32x4 a = (f32x4){0.f, 0.f, 0.f, 0.f};
            a = __builtin_amdgcn_mfma_f32_16x16x32_f16(qf0, kf0, a, 0, 0, 0);
            a = __builtin_amdgcn_mfma_f32_16x16x32_f16(qf1, kf1, a, 0, 0, 0);
            s[ct] = a;
        }
        if (has_mask) {   // rare path: fp32 mask direct, scaled to log2 domain
#pragma unroll
            for (int ct = 0; ct < 8; ++ct)
#pragma unroll
                for (int r = 0; r < 4; ++r)
                    s[ct][r] += LOG2E * Mg[(size_t)r * SEQ + c0 + ct * 16 + sub];
        }
        // row max over 128 cols + running, packed-f16 16-lane butterfly
        float mnew[4];
#pragma unroll
        for (int r = 0; r < 4; ++r) {
            float a01 = fmaxf(s[0][r], s[1][r]), a23 = fmaxf(s[2][r], s[3][r]);
            float a45 = fmaxf(s[4][r], s[5][r]), a67 = fmaxf(s[6][r], s[7][r]);
            mnew[r] = fmaxf(fmaxf(fmaxf(a01, a23), fmaxf(a45, a67)), m_run[r]);
        }
        {
            union { f16x2 h; int i; } p0, p1, v0, v1;
            p0.h = (f16x2){(f16)mnew[0], (f16)mnew[1]};
            p1.h = (f16x2){(f16)mnew[2], (f16)mnew[3]};
#pragma unroll
            for (int mk = 1; mk < 16; mk <<= 1) {
                v0.i = __shfl_xor(p0.i, mk, 64);
                v1.i = __shfl_xor(p1.i, mk, 64);
                p0.h = __builtin_elementwise_max(p0.h, v0.h);
                p1.h = __builtin_elementwise_max(p1.h, v1.h);
            }
            mnew[0] = (float)p0.h[0]; mnew[1] = (float)p0.h[1];
            mnew[2] = (float)p1.h[0]; mnew[3] = (float)p1.h[1];
        }
        float alpha[4];
#pragma unroll
        for (int r = 0; r < 4; ++r) {
            alpha[r] = exp2f(m_run[r] - mnew[r]);
            m_run[r] = mnew[r];
        }
        // rescale O and l
#pragma unroll
        for (int dt = 0; dt < 4; ++dt)
#pragma unroll
            for (int r = 0; r < 4; ++r) o[dt][r] *= alpha[r];
#pragma unroll
        for (int r = 0; r < 4; ++r) l_acc[r] *= alpha[r];

        // two 64-key halves through the shared P tile (wave-private rows)
#pragma unroll
        for (int hf = 0; hf < 2; ++hf) {
#pragma unroll
            for (int ct = 0; ct < 4; ++ct)
#pragma unroll
                for (int r = 0; r < 4; ++r) {
                    float p = exp2f(s[hf * 4 + ct][r] - mnew[r]);
                    QP[(w * 16 + quad * 4 + r) * PPIT + ct * 16 + sub] = (f16)p;
                }
            f16x4 p00 = *(const f16x4*)&QP[(w * 16 + sub) * PPIT + quad * 8];
            f16x4 p01 = *(const f16x4*)&QP[(w * 16 + sub) * PPIT + quad * 8 + 4];
            f16x4 p10 = *(const f16x4*)&QP[(w * 16 + sub) * PPIT + 32 + quad * 8];
            f16x4 p11 = *(const f16x4*)&QP[(w * 16 + sub) * PPIT + 32 + quad * 8 + 4];
            f16x8 pf0 = {p00[0], p00[1], p00[2], p00[3], p01[0], p01[1], p01[2], p01[3]};
            f16x8 pf1 = {p10[0], p10[1], p10[2], p10[3], p11[0], p11[1], p11[2], p11[3]};
            l_acc = __builtin_amdgcn_mfma_f32_16x16x32_f16(pf0, ones, l_acc, 0, 0, 0);
            l_acc = __builtin_amdgcn_mfma_f32_16x16x32_f16(pf1, ones, l_acc, 0, 0, 0);
#pragma unroll
            for (int dt = 0; dt < 4; ++dt) {
                f16x8 vf0 = *(const f16x8*)&Vt[(dt * 16 + sub) * VP + hf * 64 + quad * 8];
                f16x8 vf1 = *(const f16x8*)&Vt[(dt * 16 + sub) * VP + hf * 64 + 32 + quad * 8];
                o[dt] = __builtin_amdgcn_mfma_f32_16x16x32_f16(pf0, vf0, o[dt], 0, 0, 0);
                o[dt] = __builtin_amdgcn_mfma_f32_16x16x32_f16(pf1, vf1, o[dt], 0, 0, 0);
            }
        }

        if (c + 1 < NITER) {   // restage K/V for next chunk
            __syncthreads();   // all reads of current chunk done
            f16* kd = &Ks[krow * KP + kcb];
            *(f16x8*)(kd + 0)  = kr0;
            *(f16x8*)(kd + 8)  = kr1;
            *(f16x8*)(kd + 16) = kr2;
            *(f16x8*)(kd + 24) = kr3;
#pragma unroll
            for (int j = 0; j < 8; ++j) {
                *(f16x2*)&Vt[(w * 16 + j) * VP + 2 * lane]     = (f16x2){vr0[j], vr2[j]};
                *(f16x2*)&Vt[(w * 16 + 8 + j) * VP + 2 * lane] = (f16x2){vr1[j], vr3[j]};
            }
            __syncthreads();
        }
    }
    // epilogue
    float lsc = lscale[h];
#pragma unroll
    for (int r = 0; r < 4; ++r) {
        float inv = lsc / l_acc[r];
        int q = qb + w * 16 + quad * 4 + r;
#pragma unroll
        for (int dt = 0; dt < 4; ++dt)
            Og[((size_t)n * SEQ + q) * CH + h * 64 + dt * 16 + sub] =
                (f16)(o[dt][r] * inv);
    }
}

// ---------------------------------------------------------------------------
// Output projection, f16 inputs, reg-prefetched staging. fp32 out.
// ---------------------------------------------------------------------------
__global__ __launch_bounds__(256, 3) void out_gemm(const f16* __restrict__ A,
                                                   const f16* __restrict__ Wh,
                                                   const float* __restrict__ bias,
                                                   float* __restrict__ out)
{
    __shared__ f16 As[128 * GP];
    __shared__ f16 Bs[128 * GP];
    const int t    = threadIdx.x;
    const int w    = t >> 6;
    const int lane = t & 63;
    const int quad = lane >> 4;
    const int sub  = lane & 15;
    const int wm   = w & 1, wn = w >> 1;
    const int f0   = blockIdx.x * 128;
    const int m0   = blockIdx.y * 128;
    const int srow = t >> 1;
    const int sk   = (t & 1) * 16;

    const f16* ag = A + (size_t)(m0 + srow) * CH + sk;
    const f16* bg = Wh + (size_t)(f0 + srow) * CH + sk;
    f16x8 a0 = *(const f16x8*)(ag);
    f16x8 a1 = *(const f16x8*)(ag + 8);
    f16x8 b0 = *(const f16x8*)(bg);
    f16x8 b1 = *(const f16x8*)(bg + 8);

    f32x4 acc[4][4];
#pragma unroll
    for (int i = 0; i < 4; ++i)
#pragma unroll
        for (int j = 0; j < 4; ++j) acc[i][j] = (f32x4){0.f, 0.f, 0.f, 0.f};

    for (int k0 = 0; k0 < CH; k0 += 32) {
        __syncthreads();
        *(f16x8*)&As[srow * GP + sk + 0] = a0;
        *(f16x8*)&As[srow * GP + sk + 8] = a1;
        *(f16x8*)&Bs[srow * GP + sk + 0] = b0;
        *(f16x8*)&Bs[srow * GP + sk + 8] = b1;
        __syncthreads();
        if (k0 + 32 < CH) {
            a0 = *(const f16x8*)(ag + k0 + 32);
            a1 = *(const f16x8*)(ag + k0 + 40);
            b0 = *(const f16x8*)(bg + k0 + 32);
            b1 = *(const f16x8*)(bg + k0 + 40);
        }
        f16x8 af[4], bf[4];
#pragma unroll
        for (int i = 0; i < 4; ++i) {
            af[i] = *(const f16x8*)&As[(wm * 64 + i * 16 + sub) * GP + quad * 8];
            bf[i] = *(const f16x8*)&Bs[(wn * 64 + i * 16 + sub) * GP + quad * 8];
        }
#pragma unroll
        for (int i = 0; i < 4; ++i)
#pragma unroll
            for (int j = 0; j < 4; ++j)
                acc[i][j] = __builtin_amdgcn_mfma_f32_16x16x32_f16(af[i], bf[j], acc[i][j], 0, 0, 0);
    }
    float bb[4];
#pragma unroll
    for (int j = 0; j < 4; ++j) bb[j] = bias[f0 + wn * 64 + j * 16 + sub];
#pragma unroll
    for (int i = 0; i < 4; ++i)
#pragma unroll
        for (int r = 0; r < 4; ++r) {
            int m = m0 + wm * 64 + i * 16 + quad * 4 + r;
            float* orow = out + (size_t)m * CH + f0 + wn * 64;
#pragma unroll
            for (int j = 0; j < 4; ++j)
                orow[j * 16 + sub] = acc[i][j][r] + bb[j];
        }
}

extern "C" void kernel_launch(void* const* d_in, const int* in_sizes, int n_in,
                              void* d_out, int out_size, void* d_ws, size_t ws_size,
                              hipStream_t stream) {
    const float* x    = (const float*)d_in[0];
    const float* w1   = (const float*)d_in[1];
    const float* b1   = (const float*)d_in[2];
    const float* ls   = (const float*)d_in[3];
    const float* lrn  = (const float*)d_in[4];
    const float* w2   = (const float*)d_in[5];
    const float* b2   = (const float*)d_in[6];
    const float* msk  = (const float*)d_in[7];
    f16*   ws16 = (f16*)d_ws;
    int*   flag = (int*)(ws16 + FLAGO);
    float* out  = (float*)d_out;

    (void)hipMemsetAsync(flag, 0, 4, stream);
    hipLaunchKernelGGL(cvt_f16, dim3(4096, 4), dim3(256), 0, stream,
                       x, w1, w2, msk,
                       ws16 + XHOFF, ws16 + W1OFF, ws16 + W2OFF, flag);
    hipLaunchKernelGGL(qkv_gemm, dim3(F3 / 128, (NB * SEQ) / 128), dim3(256), 0, stream,
                       ws16 + XHOFF, ws16 + W1OFF, b1, ls, ws16);
    hipLaunchKernelGGL(attn, dim3(SEQ / 64, NH, NB), dim3(256), 0, stream,
                       ws16, ws16 + QSZ, ws16 + 2 * QSZ, msk, lrn, flag,
                       ws16 + OATT);
    hipLaunchKernelGGL(out_gemm, dim3(CH / 128, (NB * SEQ) / 128), dim3(256), 0, stream,
                       ws16 + OATT, ws16 + W2OFF, b2, out);
}